// Round 1
// baseline (1937.865 us; speedup 1.0000x reference)
//
#include <hip/hip_runtime.h>
#include <cstdint>
#include <cstddef>

constexpr int N_NODES  = 20000;
constexpr int N_EDGES  = 160000;
constexpr int N_GRAPHS = 16;
constexpr int SEQ_L    = 2048;
constexpr int F_IN     = 1024;
constexpr int D_OUT    = 128;
constexpr int N_DESC   = 80;
constexpr float SLOPE  = 0.01f;

__device__ __forceinline__ float leaky(float x) { return x > 0.f ? x : SLOPE * x; }

__device__ __forceinline__ int lower_bound_i(const int* __restrict__ arr, int n, int val) {
  int lo = 0, hi = n;
  while (lo < hi) { int mid = (lo + hi) >> 1; if (arr[mid] < val) lo = mid + 1; else hi = mid; }
  return lo;
}

// ---------------- CSR build ----------------
__global__ void count_dst(const int* __restrict__ dst, int* __restrict__ cnt) {
  int i = blockIdx.x * blockDim.x + threadIdx.x;
  if (i < N_EDGES) atomicAdd(&cnt[dst[i]], 1);
}

__global__ void dinv_k(const int* __restrict__ cnt, float* __restrict__ dinv) {
  int i = blockIdx.x * blockDim.x + threadIdx.x;
  if (i < N_NODES) dinv[i] = rsqrtf((float)(cnt[i] + 1));  // +1 self loop; always > 0
}

__global__ __launch_bounds__(1024) void scan_kernel(const int* __restrict__ cnt, int* __restrict__ rs, int n) {
  __shared__ int buf[1024];
  __shared__ int carry;
  const int t = threadIdx.x;
  if (t == 0) { carry = 0; rs[0] = 0; }
  __syncthreads();
  for (int base = 0; base < n; base += 1024) {
    int i = base + t;
    int v = (i < n) ? cnt[i] : 0;
    buf[t] = v;
    __syncthreads();
    for (int off = 1; off < 1024; off <<= 1) {
      int x = (t >= off) ? buf[t - off] : 0;
      __syncthreads();
      buf[t] += x;
      __syncthreads();
    }
    int inc = buf[t] + carry;
    if (i < n) rs[i + 1] = inc;
    __syncthreads();
    if (t == 1023) carry = inc;
    __syncthreads();
  }
}

__global__ void fill_csr(const int* __restrict__ src, const int* __restrict__ dst,
                         const int* __restrict__ rs, int* __restrict__ cursor,
                         int* __restrict__ esrc) {
  int i = blockIdx.x * blockDim.x + threadIdx.x;
  if (i < N_EDGES) {
    int d = dst[i];
    int pos = rs[d] + atomicAdd(&cursor[d], 1);
    esrc[pos] = src[i];
  }
}

// ---------------- fp32 GEMM: C[M,N] = A[M,K] @ B[K,N] ----------------
__global__ __launch_bounds__(256) void sgemm_nn(const float* __restrict__ A,
                                                const float* __restrict__ Bm,
                                                float* __restrict__ C,
                                                int M, int N, int K) {
  constexpr int BM = 64, BN = 64, BK = 16;
  __shared__ float As[BK][BM + 4];
  __shared__ float Bs[BK][BN + 4];
  const int t = threadIdx.x;
  const int bm = blockIdx.x * BM;
  const int bn = blockIdx.y * BN;
  const int tm = (t >> 4) << 2;   // 0..60 step 4
  const int tn = (t & 15) << 2;   // 0..60 step 4
  const int lr  = t >> 2;         // A-load row 0..63
  const int lk  = (t & 3) << 2;   // A-load k {0,4,8,12}
  const int lkb = t >> 4;         // B-load k 0..15
  const int lnb = (t & 15) << 2;  // B-load n
  float acc[4][4] = {};
  for (int k0 = 0; k0 < K; k0 += BK) {
    int arow = bm + lr;
    float4 av = make_float4(0.f, 0.f, 0.f, 0.f);
    if (arow < M) av = *(const float4*)(A + (size_t)arow * K + k0 + lk);
    As[lk + 0][lr] = av.x; As[lk + 1][lr] = av.y; As[lk + 2][lr] = av.z; As[lk + 3][lr] = av.w;
    float4 bv = *(const float4*)(Bm + (size_t)(k0 + lkb) * N + bn + lnb);
    Bs[lkb][lnb + 0] = bv.x; Bs[lkb][lnb + 1] = bv.y; Bs[lkb][lnb + 2] = bv.z; Bs[lkb][lnb + 3] = bv.w;
    __syncthreads();
#pragma unroll
    for (int k = 0; k < BK; ++k) {
      float a[4], b[4];
#pragma unroll
      for (int i = 0; i < 4; ++i) a[i] = As[k][tm + i];
#pragma unroll
      for (int j = 0; j < 4; ++j) b[j] = Bs[k][tn + j];
#pragma unroll
      for (int i = 0; i < 4; ++i)
#pragma unroll
        for (int j = 0; j < 4; ++j) acc[i][j] = fmaf(a[i], b[j], acc[i][j]);
    }
    __syncthreads();
  }
#pragma unroll
  for (int i = 0; i < 4; ++i) {
    int row = bm + tm + i;
    if (row < M) {
#pragma unroll
      for (int j = 0; j < 4; ++j) C[(size_t)row * N + bn + tn + j] = acc[i][j];
    }
  }
}

// ---------------- GCN aggregate (CSR gather) + bias + leaky ----------------
__global__ __launch_bounds__(256) void gcn_agg(const float* __restrict__ h,
                                               const int* __restrict__ rs,
                                               const int* __restrict__ esrc,
                                               const float* __restrict__ dinv,
                                               const float* __restrict__ bias,
                                               float* __restrict__ y) {
  const int node = blockIdx.x;
  const int t = threadIdx.x;  // f = 4t
  const float din = dinv[node];
  float4 hv = ((const float4*)(h + (size_t)node * F_IN))[t];
  const float w0 = din * din;
  float a0 = hv.x * w0, a1 = hv.y * w0, a2 = hv.z * w0, a3 = hv.w * w0;
  const int e0 = rs[node], e1 = rs[node + 1];
  for (int e = e0; e < e1; ++e) {
    int s = esrc[e];
    float wgt = dinv[s] * din;
    float4 v = ((const float4*)(h + (size_t)s * F_IN))[t];
    a0 = fmaf(v.x, wgt, a0); a1 = fmaf(v.y, wgt, a1);
    a2 = fmaf(v.z, wgt, a2); a3 = fmaf(v.w, wgt, a3);
  }
  float4 bv = ((const float4*)bias)[t];
  float4 o;
  o.x = leaky(a0 + bv.x); o.y = leaky(a1 + bv.y);
  o.z = leaky(a2 + bv.z); o.w = leaky(a3 + bv.w);
  ((float4*)(y + (size_t)node * F_IN))[t] = o;
}

// ---------------- mean pool (partial sums, 8 slices/graph) ----------------
__global__ __launch_bounds__(256) void pool_partial(const float* __restrict__ y,
                                                    const int* __restrict__ batch,
                                                    float* __restrict__ pool) {
  const int g = blockIdx.x;
  const int slice = blockIdx.y;  // 8 slices
  const int t = threadIdx.x;
  int lo = lower_bound_i(batch, N_NODES, g);
  int hi = lower_bound_i(batch, N_NODES, g + 1);
  int cnt = hi - lo;
  int per = (cnt + 7) >> 3;
  int a = lo + slice * per;
  int b = min(a + per, hi);
  float s0 = 0.f, s1 = 0.f, s2 = 0.f, s3 = 0.f;
  for (int node = a; node < b; ++node) {
    float4 v = ((const float4*)(y + (size_t)node * F_IN))[t];
    s0 += v.x; s1 += v.y; s2 += v.z; s3 += v.w;
  }
  if (a < b) {
    atomicAdd(&pool[g * F_IN + 4 * t + 0], s0);
    atomicAdd(&pool[g * F_IN + 4 * t + 1], s1);
    atomicAdd(&pool[g * F_IN + 4 * t + 2], s2);
    atomicAdd(&pool[g * F_IN + 4 * t + 3], s3);
  }
}

// ---------------- FC [16,1024]@[1024,128] + bias + leaky -> combined cols ----------------
__global__ __launch_bounds__(128) void fc_kernel(const float* __restrict__ pool,
                                                 const int* __restrict__ batch,
                                                 const float* __restrict__ W,
                                                 const float* __restrict__ bias,
                                                 float* __restrict__ combined, int col_off) {
  const int g = blockIdx.x;
  const int t = threadIdx.x;  // 128
  __shared__ float p[F_IN];
  int lo = lower_bound_i(batch, N_NODES, g);
  int hi = lower_bound_i(batch, N_NODES, g + 1);
  float inv = 1.0f / (float)max(hi - lo, 1);
  for (int k = t; k < F_IN; k += 128) p[k] = pool[g * F_IN + k] * inv;
  __syncthreads();
  float acc = 0.f;
  for (int k = 0; k < F_IN; ++k) acc = fmaf(p[k], W[k * D_OUT + t], acc);
  combined[g * (6 * D_OUT) + col_off + t] = leaky(acc + bias[t]);
}

// ---------------- conv1d(k=1) partial max over a 128-chunk of L ----------------
__global__ __launch_bounds__(128) void conv_partial(const float* __restrict__ m,
                                                    const float* __restrict__ W,
                                                    float* __restrict__ pmax) {
  const int g = blockIdx.y;
  const int ch = blockIdx.x;  // 16 chunks of 128
  const int t = threadIdx.x;  // d
  __shared__ float ms[128 * N_DESC];
  const float* mg = m + ((size_t)g * SEQ_L + (size_t)ch * 128) * N_DESC;
  for (int i = t; i < 128 * N_DESC; i += 128) ms[i] = mg[i];
  float w[N_DESC];
#pragma unroll
  for (int k = 0; k < N_DESC; ++k) w[k] = W[k * D_OUT + t];
  __syncthreads();
  float best = -3.4e38f;
  for (int l = 0; l < 128; ++l) {
    float acc = 0.f;
#pragma unroll
    for (int k = 0; k < N_DESC; ++k) acc = fmaf(ms[l * N_DESC + k], w[k], acc);
    best = fmaxf(best, acc);
  }
  pmax[(g * 16 + ch) * D_OUT + t] = best;
}

__global__ void conv_reduce(const float* __restrict__ pmax,
                            const float* __restrict__ b0, const float* __restrict__ b1,
                            const float* __restrict__ b2, const float* __restrict__ b3,
                            float* __restrict__ combined) {
  int i = blockIdx.x * blockDim.x + threadIdx.x;  // 4*16*128
  if (i >= 4 * N_GRAPHS * D_OUT) return;
  int br = i >> 11;
  int g = (i >> 7) & 15;
  int d = i & 127;
  const float* pm = pmax + ((size_t)(br * N_GRAPHS + g) * 16) * D_OUT + d;
  float best = -3.4e38f;
#pragma unroll
  for (int ch = 0; ch < 16; ++ch) best = fmaxf(best, pm[ch * D_OUT]);
  const float* bias = br == 0 ? b0 : br == 1 ? b1 : br == 2 ? b2 : b3;
  combined[g * (6 * D_OUT) + 2 * D_OUT + br * D_OUT + d] = leaky(best + bias[d]);
}

// ---------------- final linear [16,768]@[768,1] ----------------
__global__ __launch_bounds__(256) void final_kernel(const float* __restrict__ combined,
                                                    const float* __restrict__ Wf,
                                                    const float* __restrict__ bf,
                                                    float* __restrict__ out) {
  const int g = blockIdx.x;
  const int t = threadIdx.x;
  float acc = 0.f;
  for (int k = t; k < 6 * D_OUT; k += 256) acc = fmaf(combined[g * 6 * D_OUT + k], Wf[k], acc);
  __shared__ float red[256];
  red[t] = acc;
  __syncthreads();
  for (int s = 128; s > 0; s >>= 1) {
    if (t < s) red[t] += red[t + s];
    __syncthreads();
  }
  if (t == 0) out[g] = red[0] + bf[0];
}

extern "C" void kernel_launch(void* const* d_in, const int* in_sizes, int n_in,
                              void* d_out, int out_size, void* d_ws, size_t ws_size,
                              hipStream_t stream) {
  const float* p1x  = (const float*)d_in[0];
  const int*   e1   = (const int*)d_in[1];
  const int*   bt1  = (const int*)d_in[2];
  const float* p2x  = (const float*)d_in[3];
  const int*   e2   = (const int*)d_in[4];
  const int*   bt2  = (const int*)d_in[5];
  const float* m1s  = (const float*)d_in[6];
  const float* m1f  = (const float*)d_in[7];
  const float* m2s  = (const float*)d_in[8];
  const float* m2f  = (const float*)d_in[9];
  const float* Wg1  = (const float*)d_in[10];
  const float* bg1  = (const float*)d_in[11];
  const float* Wfc1 = (const float*)d_in[12];
  const float* bfc1 = (const float*)d_in[13];
  const float* Wg2  = (const float*)d_in[14];
  const float* bg2  = (const float*)d_in[15];
  const float* Wfc2 = (const float*)d_in[16];
  const float* bfc2 = (const float*)d_in[17];
  const float* Wm1s = (const float*)d_in[18];
  const float* bm1s = (const float*)d_in[19];
  const float* Wm1f = (const float*)d_in[20];
  const float* bm1f = (const float*)d_in[21];
  const float* Wm2s = (const float*)d_in[22];
  const float* bm2s = (const float*)d_in[23];
  const float* Wm2f = (const float*)d_in[24];
  const float* bm2f = (const float*)d_in[25];
  const float* Wfin = (const float*)d_in[26];
  const float* bfin = (const float*)d_in[27];
  float* out = (float*)d_out;

  char* base = (char*)d_ws;
  size_t off = 0;
  auto alloc = [&](size_t bytes) -> void* {
    void* p = base + off;
    off = (off + bytes + 255) & ~(size_t)255;
    return p;
  };
  float* h      = (float*)alloc((size_t)N_NODES * F_IN * 4);
  float* yb     = (float*)alloc((size_t)N_NODES * F_IN * 4);
  int*   cnt    = (int*)alloc((size_t)N_NODES * 4);
  float* dinv   = (float*)alloc((size_t)N_NODES * 4);
  int*   rs     = (int*)alloc((size_t)(N_NODES + 1) * 4);
  int*   cursor = (int*)alloc((size_t)N_NODES * 4);
  int*   esrc   = (int*)alloc((size_t)N_EDGES * 4);
  float* pool   = (float*)alloc((size_t)N_GRAPHS * F_IN * 4);
  float* combined = (float*)alloc((size_t)N_GRAPHS * 6 * D_OUT * 4);
  float* pmax   = (float*)alloc((size_t)4 * N_GRAPHS * 16 * D_OUT * 4);
  (void)ws_size; (void)in_sizes; (void)n_in; (void)out_size;

  // descriptor conv branches (independent of GCN work)
  dim3 cgrid(16, N_GRAPHS);
  const size_t pbr = (size_t)N_GRAPHS * 16 * D_OUT;
  conv_partial<<<cgrid, 128, 0, stream>>>(m1s, Wm1s, pmax + 0 * pbr);
  conv_partial<<<cgrid, 128, 0, stream>>>(m1f, Wm1f, pmax + 1 * pbr);
  conv_partial<<<cgrid, 128, 0, stream>>>(m2s, Wm2s, pmax + 2 * pbr);
  conv_partial<<<cgrid, 128, 0, stream>>>(m2f, Wm2f, pmax + 3 * pbr);
  conv_reduce<<<(4 * N_GRAPHS * D_OUT + 255) / 256, 256, 0, stream>>>(pmax, bm1s, bm1f, bm2s, bm2f, combined);

  for (int br = 0; br < 2; ++br) {
    const float* x   = br ? p2x : p1x;
    const int*   ei  = br ? e2 : e1;
    const int*   bt  = br ? bt2 : bt1;
    const float* Wg  = br ? Wg2 : Wg1;
    const float* bg  = br ? bg2 : bg1;
    const float* Wfc = br ? Wfc2 : Wfc1;
    const float* bfc = br ? bfc2 : bfc1;
    const int* srcv = ei;
    const int* dstv = ei + N_EDGES;

    hipMemsetAsync(cnt, 0, (size_t)N_NODES * 4, stream);
    hipMemsetAsync(cursor, 0, (size_t)N_NODES * 4, stream);
    hipMemsetAsync(pool, 0, (size_t)N_GRAPHS * F_IN * 4, stream);

    count_dst<<<(N_EDGES + 255) / 256, 256, 0, stream>>>(dstv, cnt);
    dinv_k<<<(N_NODES + 255) / 256, 256, 0, stream>>>(cnt, dinv);
    scan_kernel<<<1, 1024, 0, stream>>>(cnt, rs, N_NODES);
    fill_csr<<<(N_EDGES + 255) / 256, 256, 0, stream>>>(srcv, dstv, rs, cursor, esrc);

    sgemm_nn<<<dim3((N_NODES + 63) / 64, F_IN / 64), 256, 0, stream>>>(x, Wg, h, N_NODES, F_IN, F_IN);
    gcn_agg<<<N_NODES, 256, 0, stream>>>(h, rs, esrc, dinv, bg, yb);
    pool_partial<<<dim3(N_GRAPHS, 8), 256, 0, stream>>>(yb, bt, pool);
    fc_kernel<<<N_GRAPHS, 128, 0, stream>>>(pool, bt, Wfc, bfc, combined, br * D_OUT);
  }

  final_kernel<<<N_GRAPHS, 256, 0, stream>>>(combined, Wfin, bfin, out);
}

// Round 2
// 853.674 us; speedup vs baseline: 2.2700x; 2.2700x over previous
//
#include <hip/hip_runtime.h>
#include <cstdint>
#include <cstddef>

constexpr int N_NODES  = 20000;
constexpr int N_PAD    = 20096;   // 157 * 128
constexpr int N_EDGES  = 160000;
constexpr int N_GRAPHS = 16;
constexpr int SEQ_L    = 2048;
constexpr int F_IN     = 1024;
constexpr int D_OUT    = 128;
constexpr int N_DESC   = 80;
constexpr float SLOPE  = 0.01f;

typedef short bf16x8 __attribute__((ext_vector_type(8)));
typedef float f32x4  __attribute__((ext_vector_type(4)));

__device__ __forceinline__ float leaky(float x) { return x > 0.f ? x : SLOPE * x; }
__device__ __forceinline__ ushort f2bf(float f) {
  uint32_t u = __float_as_uint(f);
  uint32_t r = (u + 0x7FFFu + ((u >> 16) & 1u)) >> 16;
  return (ushort)r;
}
__device__ __forceinline__ float bf2f(ushort u) { return __uint_as_float(((uint32_t)u) << 16); }

__device__ __forceinline__ int lower_bound_i(const int* __restrict__ arr, int n, int val) {
  int lo = 0, hi = n;
  while (lo < hi) { int mid = (lo + hi) >> 1; if (arr[mid] < val) lo = mid + 1; else hi = mid; }
  return lo;
}

// ---------------- conversions ----------------
// x [20000,1024] f32 -> [20096,1024] bf16 (pad rows zero)
__global__ __launch_bounds__(256) void cast_pad(const float* __restrict__ in, ushort* __restrict__ out) {
  size_t i = ((size_t)blockIdx.x * 256 + threadIdx.x) * 4;  // element index
  if (i >= (size_t)N_PAD * F_IN) return;
  int row = (int)(i >> 10);
  ushort4 o;
  if (row < N_NODES) {
    float4 v = *(const float4*)(in + i);
    o.x = f2bf(v.x); o.y = f2bf(v.y); o.z = f2bf(v.z); o.w = f2bf(v.w);
  } else {
    o.x = o.y = o.z = o.w = 0;
  }
  *(ushort4*)(out + i) = o;
}

// W [K=1024][N=1024] f32 -> Wt [N][K] bf16
__global__ __launch_bounds__(256) void convT_bf16(const float* __restrict__ W, ushort* __restrict__ Wt) {
  __shared__ float tile[32][33];
  const int k0 = blockIdx.x * 32, n0 = blockIdx.y * 32;
  const int tc = threadIdx.x & 31, tr = threadIdx.x >> 5;  // tr 0..7
#pragma unroll
  for (int q = 0; q < 4; ++q) {
    int r = tr + q * 8;
    tile[r][tc] = W[(size_t)(k0 + r) * F_IN + n0 + tc];
  }
  __syncthreads();
#pragma unroll
  for (int q = 0; q < 4; ++q) {
    int r = tr + q * 8;
    Wt[(size_t)(n0 + r) * F_IN + k0 + tc] = f2bf(tile[tc][r]);
  }
}

// ---------------- CSR build ----------------
__global__ void count_dst(const int* __restrict__ dst, int* __restrict__ cnt) {
  int i = blockIdx.x * blockDim.x + threadIdx.x;
  if (i < N_EDGES) atomicAdd(&cnt[dst[i]], 1);
}

__global__ void dinv_k(const int* __restrict__ cnt, float* __restrict__ dinv) {
  int i = blockIdx.x * blockDim.x + threadIdx.x;
  if (i < N_NODES) dinv[i] = rsqrtf((float)(cnt[i] + 1));  // +1 self loop
}

__global__ __launch_bounds__(1024) void scan_kernel(const int* __restrict__ cnt, int* __restrict__ rs, int n) {
  __shared__ int wsum[16];
  __shared__ int carry_s;
  const int t = threadIdx.x;
  const int lane = t & 63, wid = t >> 6;
  if (t == 0) { carry_s = 0; rs[0] = 0; }
  __syncthreads();
  for (int base = 0; base < n; base += 1024) {
    int i = base + t;
    int x = (i < n) ? cnt[i] : 0;
#pragma unroll
    for (int off = 1; off < 64; off <<= 1) {
      int v = __shfl_up(x, off, 64);
      if (lane >= off) x += v;
    }
    if (lane == 63) wsum[wid] = x;
    __syncthreads();
    if (wid == 0) {
      int s = (lane < 16) ? wsum[lane] : 0;
#pragma unroll
      for (int off = 1; off < 16; off <<= 1) {
        int v = __shfl_up(s, off, 64);
        if (lane >= off) s += v;
      }
      if (lane < 16) wsum[lane] = s;
    }
    __syncthreads();
    int inc = x + (wid > 0 ? wsum[wid - 1] : 0) + carry_s;
    if (i < n) rs[i + 1] = inc;
    __syncthreads();
    if (t == 1023) carry_s = inc;
    __syncthreads();
  }
}

__global__ void fill_csr(const int* __restrict__ src, const int* __restrict__ dst,
                         const int* __restrict__ rs, int* __restrict__ cursor,
                         int* __restrict__ esrc) {
  int i = blockIdx.x * blockDim.x + threadIdx.x;
  if (i < N_EDGES) {
    int d = dst[i];
    int pos = rs[d] + atomicAdd(&cursor[d], 1);
    esrc[pos] = src[i];
  }
}

// ---------------- bf16 MFMA GEMM: C[M,1024] = A[M,1024] @ Bt^T, all bf16 ----------------
// A [N_PAD][1024] bf16 row-major; Bt [1024][1024] bf16 = B^T (n,k); C [N_PAD][1024] bf16
__global__ __launch_bounds__(256) void gemm_bf16(const ushort* __restrict__ A,
                                                 const ushort* __restrict__ Bt,
                                                 ushort* __restrict__ C) {
  __shared__ ushort lA[128 * 32];
  __shared__ ushort lB[128 * 32];
  const int t = threadIdx.x;
  const int lane = t & 63;
  const int w = t >> 6;            // wave 0..3
  const int wr = w >> 1, wc = w & 1;
  const int brow = blockIdx.x * 128;
  const int bcol = blockIdx.y * 128;

  const int si = w * 2;                        // 2 staging instrs per wave per tile
  const int srow0 = si * 16 + (lane >> 2);
  const int srow1 = (si + 1) * 16 + (lane >> 2);
  const int skk = (lane & 3) * 8;
  const ushort* gA0 = A + (size_t)(brow + srow0) * F_IN + skk;
  const ushort* gA1 = A + (size_t)(brow + srow1) * F_IN + skk;
  const ushort* gB0 = Bt + (size_t)(bcol + srow0) * F_IN + skk;
  const ushort* gB1 = Bt + (size_t)(bcol + srow1) * F_IN + skk;
  ushort* lA0 = lA + si * 512;
  ushort* lA1 = lA + (si + 1) * 512;
  ushort* lB0 = lB + si * 512;
  ushort* lB1 = lB + (si + 1) * 512;

  f32x4 acc[4][4] = {};
  const int frow = lane & 15;
  const int fk = (lane >> 4) * 8;

  for (int k0 = 0; k0 < F_IN; k0 += 32) {
    __builtin_amdgcn_global_load_lds((const __attribute__((address_space(1))) void*)(gA0 + k0),
                                     (__attribute__((address_space(3))) void*)lA0, 16, 0, 0);
    __builtin_amdgcn_global_load_lds((const __attribute__((address_space(1))) void*)(gA1 + k0),
                                     (__attribute__((address_space(3))) void*)lA1, 16, 0, 0);
    __builtin_amdgcn_global_load_lds((const __attribute__((address_space(1))) void*)(gB0 + k0),
                                     (__attribute__((address_space(3))) void*)lB0, 16, 0, 0);
    __builtin_amdgcn_global_load_lds((const __attribute__((address_space(1))) void*)(gB1 + k0),
                                     (__attribute__((address_space(3))) void*)lB1, 16, 0, 0);
    __syncthreads();
    bf16x8 af[4], bfr[4];
#pragma unroll
    for (int m = 0; m < 4; ++m)
      af[m] = *(const bf16x8*)(lA + (wr * 64 + m * 16 + frow) * 32 + fk);
#pragma unroll
    for (int n = 0; n < 4; ++n)
      bfr[n] = *(const bf16x8*)(lB + (wc * 64 + n * 16 + frow) * 32 + fk);
#pragma unroll
    for (int m = 0; m < 4; ++m)
#pragma unroll
      for (int n = 0; n < 4; ++n)
        acc[m][n] = __builtin_amdgcn_mfma_f32_16x16x32_bf16(af[m], bfr[n], acc[m][n], 0, 0, 0);
    __syncthreads();
  }

#pragma unroll
  for (int m = 0; m < 4; ++m) {
    const int row0 = brow + wr * 64 + m * 16 + (lane >> 4) * 4;
#pragma unroll
    for (int n = 0; n < 4; ++n) {
      const int col = bcol + wc * 64 + n * 16 + (lane & 15);
#pragma unroll
      for (int j = 0; j < 4; ++j)
        C[(size_t)(row0 + j) * F_IN + col] = f2bf(acc[m][n][j]);
    }
  }
}

// ---------------- GCN aggregate (CSR gather, bf16 h) + bias + leaky ----------------
__global__ __launch_bounds__(256) void gcn_agg(const ushort* __restrict__ h,
                                               const int* __restrict__ rs,
                                               const int* __restrict__ esrc,
                                               const float* __restrict__ dinv,
                                               const float* __restrict__ bias,
                                               float* __restrict__ y) {
  const int node = blockIdx.x;
  const int t = threadIdx.x;  // covers elems 4t..4t+3
  const float din = dinv[node];
  ushort4 hv = ((const ushort4*)(h + (size_t)node * F_IN))[t];
  const float w0 = din * din;
  float a0 = bf2f(hv.x) * w0, a1 = bf2f(hv.y) * w0, a2 = bf2f(hv.z) * w0, a3 = bf2f(hv.w) * w0;
  const int e0 = rs[node], e1 = rs[node + 1];
  for (int e = e0; e < e1; ++e) {
    int s = esrc[e];
    float wgt = dinv[s] * din;
    ushort4 v = ((const ushort4*)(h + (size_t)s * F_IN))[t];
    a0 = fmaf(bf2f(v.x), wgt, a0); a1 = fmaf(bf2f(v.y), wgt, a1);
    a2 = fmaf(bf2f(v.z), wgt, a2); a3 = fmaf(bf2f(v.w), wgt, a3);
  }
  float4 bv = ((const float4*)bias)[t];
  float4 o;
  o.x = leaky(a0 + bv.x); o.y = leaky(a1 + bv.y);
  o.z = leaky(a2 + bv.z); o.w = leaky(a3 + bv.w);
  ((float4*)(y + (size_t)node * F_IN))[t] = o;
}

// ---------------- mean pool (partial sums, 8 slices/graph) ----------------
__global__ __launch_bounds__(256) void pool_partial(const float* __restrict__ y,
                                                    const int* __restrict__ batch,
                                                    float* __restrict__ pool) {
  const int g = blockIdx.x;
  const int slice = blockIdx.y;
  const int t = threadIdx.x;
  int lo = lower_bound_i(batch, N_NODES, g);
  int hi = lower_bound_i(batch, N_NODES, g + 1);
  int cnt = hi - lo;
  int per = (cnt + 7) >> 3;
  int a = lo + slice * per;
  int b = min(a + per, hi);
  float s0 = 0.f, s1 = 0.f, s2 = 0.f, s3 = 0.f;
  for (int node = a; node < b; ++node) {
    float4 v = ((const float4*)(y + (size_t)node * F_IN))[t];
    s0 += v.x; s1 += v.y; s2 += v.z; s3 += v.w;
  }
  if (a < b) {
    atomicAdd(&pool[g * F_IN + 4 * t + 0], s0);
    atomicAdd(&pool[g * F_IN + 4 * t + 1], s1);
    atomicAdd(&pool[g * F_IN + 4 * t + 2], s2);
    atomicAdd(&pool[g * F_IN + 4 * t + 3], s3);
  }
}

// ---------------- FC [16,1024]@[1024,128] + bias + leaky ----------------
__global__ __launch_bounds__(128) void fc_kernel(const float* __restrict__ pool,
                                                 const int* __restrict__ batch,
                                                 const float* __restrict__ W,
                                                 const float* __restrict__ bias,
                                                 float* __restrict__ combined, int col_off) {
  const int g = blockIdx.x;
  const int t = threadIdx.x;
  __shared__ float p[F_IN];
  int lo = lower_bound_i(batch, N_NODES, g);
  int hi = lower_bound_i(batch, N_NODES, g + 1);
  float inv = 1.0f / (float)max(hi - lo, 1);
  for (int k = t; k < F_IN; k += 128) p[k] = pool[g * F_IN + k] * inv;
  __syncthreads();
  float acc = 0.f;
  for (int k = 0; k < F_IN; ++k) acc = fmaf(p[k], W[k * D_OUT + t], acc);
  combined[g * (6 * D_OUT) + col_off + t] = leaky(acc + bias[t]);
}

// ---------------- conv1d(k=1) partial max ----------------
__global__ __launch_bounds__(128) void conv_partial(const float* __restrict__ m,
                                                    const float* __restrict__ W,
                                                    float* __restrict__ pmax) {
  const int g = blockIdx.y;
  const int ch = blockIdx.x;
  const int t = threadIdx.x;
  __shared__ float ms[128 * N_DESC];
  const float* mg = m + ((size_t)g * SEQ_L + (size_t)ch * 128) * N_DESC;
  for (int i = t; i < 128 * N_DESC; i += 128) ms[i] = mg[i];
  float w[N_DESC];
#pragma unroll
  for (int k = 0; k < N_DESC; ++k) w[k] = W[k * D_OUT + t];
  __syncthreads();
  float best = -3.4e38f;
  for (int l = 0; l < 128; ++l) {
    float acc = 0.f;
#pragma unroll
    for (int k = 0; k < N_DESC; ++k) acc = fmaf(ms[l * N_DESC + k], w[k], acc);
    best = fmaxf(best, acc);
  }
  pmax[(g * 16 + ch) * D_OUT + t] = best;
}

__global__ void conv_reduce(const float* __restrict__ pmax,
                            const float* __restrict__ b0, const float* __restrict__ b1,
                            const float* __restrict__ b2, const float* __restrict__ b3,
                            float* __restrict__ combined) {
  int i = blockIdx.x * blockDim.x + threadIdx.x;
  if (i >= 4 * N_GRAPHS * D_OUT) return;
  int br = i >> 11;
  int g = (i >> 7) & 15;
  int d = i & 127;
  const float* pm = pmax + ((size_t)(br * N_GRAPHS + g) * 16) * D_OUT + d;
  float best = -3.4e38f;
#pragma unroll
  for (int ch = 0; ch < 16; ++ch) best = fmaxf(best, pm[ch * D_OUT]);
  const float* bias = br == 0 ? b0 : br == 1 ? b1 : br == 2 ? b2 : b3;
  combined[g * (6 * D_OUT) + 2 * D_OUT + br * D_OUT + d] = leaky(best + bias[d]);
}

// ---------------- final linear ----------------
__global__ __launch_bounds__(256) void final_kernel(const float* __restrict__ combined,
                                                    const float* __restrict__ Wf,
                                                    const float* __restrict__ bf,
                                                    float* __restrict__ out) {
  const int g = blockIdx.x;
  const int t = threadIdx.x;
  float acc = 0.f;
  for (int k = t; k < 6 * D_OUT; k += 256) acc = fmaf(combined[g * 6 * D_OUT + k], Wf[k], acc);
  __shared__ float red[256];
  red[t] = acc;
  __syncthreads();
  for (int s = 128; s > 0; s >>= 1) {
    if (t < s) red[t] += red[t + s];
    __syncthreads();
  }
  if (t == 0) out[g] = red[0] + bf[0];
}

extern "C" void kernel_launch(void* const* d_in, const int* in_sizes, int n_in,
                              void* d_out, int out_size, void* d_ws, size_t ws_size,
                              hipStream_t stream) {
  const float* p1x  = (const float*)d_in[0];
  const int*   e1   = (const int*)d_in[1];
  const int*   bt1  = (const int*)d_in[2];
  const float* p2x  = (const float*)d_in[3];
  const int*   e2   = (const int*)d_in[4];
  const int*   bt2  = (const int*)d_in[5];
  const float* m1s  = (const float*)d_in[6];
  const float* m1f  = (const float*)d_in[7];
  const float* m2s  = (const float*)d_in[8];
  const float* m2f  = (const float*)d_in[9];
  const float* Wg1  = (const float*)d_in[10];
  const float* bg1  = (const float*)d_in[11];
  const float* Wfc1 = (const float*)d_in[12];
  const float* bfc1 = (const float*)d_in[13];
  const float* Wg2  = (const float*)d_in[14];
  const float* bg2  = (const float*)d_in[15];
  const float* Wfc2 = (const float*)d_in[16];
  const float* bfc2 = (const float*)d_in[17];
  const float* Wm1s = (const float*)d_in[18];
  const float* bm1s = (const float*)d_in[19];
  const float* Wm1f = (const float*)d_in[20];
  const float* bm1f = (const float*)d_in[21];
  const float* Wm2s = (const float*)d_in[22];
  const float* bm2s = (const float*)d_in[23];
  const float* Wm2f = (const float*)d_in[24];
  const float* bm2f = (const float*)d_in[25];
  const float* Wfin = (const float*)d_in[26];
  const float* bfin = (const float*)d_in[27];
  float* out = (float*)d_out;

  char* base = (char*)d_ws;
  size_t off = 0;
  auto alloc = [&](size_t bytes) -> void* {
    void* p = base + off;
    off = (off + bytes + 255) & ~(size_t)255;
    return p;
  };
  ushort* xbf   = (ushort*)alloc((size_t)N_PAD * F_IN * 2);
  ushort* wtbf  = (ushort*)alloc((size_t)F_IN * F_IN * 2);
  ushort* h     = (ushort*)alloc((size_t)N_PAD * F_IN * 2);
  float*  yb    = (float*)alloc((size_t)N_NODES * F_IN * 4);
  int*    cnt   = (int*)alloc((size_t)N_NODES * 4);
  float*  dinv  = (float*)alloc((size_t)N_NODES * 4);
  int*    rs    = (int*)alloc((size_t)(N_NODES + 1) * 4);
  int*    cursor= (int*)alloc((size_t)N_NODES * 4);
  int*    esrc  = (int*)alloc((size_t)N_EDGES * 4);
  float*  pool  = (float*)alloc((size_t)N_GRAPHS * F_IN * 4);
  float*  combined = (float*)alloc((size_t)N_GRAPHS * 6 * D_OUT * 4);
  float*  pmax  = (float*)alloc((size_t)4 * N_GRAPHS * 16 * D_OUT * 4);
  (void)ws_size; (void)in_sizes; (void)n_in; (void)out_size;

  // descriptor conv branches first (independent)
  dim3 cgrid(16, N_GRAPHS);
  const size_t pbr = (size_t)N_GRAPHS * 16 * D_OUT;
  conv_partial<<<cgrid, 128, 0, stream>>>(m1s, Wm1s, pmax + 0 * pbr);
  conv_partial<<<cgrid, 128, 0, stream>>>(m1f, Wm1f, pmax + 1 * pbr);
  conv_partial<<<cgrid, 128, 0, stream>>>(m2s, Wm2s, pmax + 2 * pbr);
  conv_partial<<<cgrid, 128, 0, stream>>>(m2f, Wm2f, pmax + 3 * pbr);
  conv_reduce<<<(4 * N_GRAPHS * D_OUT + 255) / 256, 256, 0, stream>>>(pmax, bm1s, bm1f, bm2s, bm2f, combined);

  const int cast_blocks = (int)(((size_t)N_PAD * F_IN / 4 + 255) / 256);

  for (int br = 0; br < 2; ++br) {
    const float* x   = br ? p2x : p1x;
    const int*   ei  = br ? e2 : e1;
    const int*   bt  = br ? bt2 : bt1;
    const float* Wg  = br ? Wg2 : Wg1;
    const float* bg  = br ? bg2 : bg1;
    const float* Wfc = br ? Wfc2 : Wfc1;
    const float* bfc = br ? bfc2 : bfc1;
    const int* srcv = ei;
    const int* dstv = ei + N_EDGES;

    hipMemsetAsync(cnt, 0, (size_t)N_NODES * 4, stream);
    hipMemsetAsync(cursor, 0, (size_t)N_NODES * 4, stream);
    hipMemsetAsync(pool, 0, (size_t)N_GRAPHS * F_IN * 4, stream);

    cast_pad<<<cast_blocks, 256, 0, stream>>>(x, xbf);
    convT_bf16<<<dim3(32, 32), 256, 0, stream>>>(Wg, wtbf);
    count_dst<<<(N_EDGES + 255) / 256, 256, 0, stream>>>(dstv, cnt);
    dinv_k<<<(N_NODES + 255) / 256, 256, 0, stream>>>(cnt, dinv);
    scan_kernel<<<1, 1024, 0, stream>>>(cnt, rs, N_NODES);
    fill_csr<<<(N_EDGES + 255) / 256, 256, 0, stream>>>(srcv, dstv, rs, cursor, esrc);

    gemm_bf16<<<dim3(N_PAD / 128, F_IN / 128), 256, 0, stream>>>(xbf, wtbf, h);
    gcn_agg<<<N_NODES, 256, 0, stream>>>(h, rs, esrc, dinv, bg, yb);
    pool_partial<<<dim3(N_GRAPHS, 8), 256, 0, stream>>>(yb, bt, pool);
    fc_kernel<<<N_GRAPHS, 128, 0, stream>>>(pool, bt, Wfc, bfc, combined, br * D_OUT);
  }

  final_kernel<<<N_GRAPHS, 256, 0, stream>>>(combined, Wfin, bfin, out);
}

// Round 3
// 659.701 us; speedup vs baseline: 2.9375x; 1.2940x over previous
//
#include <hip/hip_runtime.h>
#include <cstdint>
#include <cstddef>

constexpr int N_NODES  = 20000;
constexpr int N_PAD    = 20096;   // 157 * 128
constexpr int N_EDGES  = 160000;
constexpr int N_GRAPHS = 16;
constexpr int SEQ_L    = 2048;
constexpr int F_IN     = 1024;
constexpr int D_OUT    = 128;
constexpr int N_DESC   = 80;
constexpr int L_CHUNK  = 64;
constexpr int N_CHUNKS = SEQ_L / L_CHUNK;  // 32
constexpr float SLOPE  = 0.01f;

typedef short bf16x8 __attribute__((ext_vector_type(8)));
typedef float f32x4  __attribute__((ext_vector_type(4)));

__device__ __forceinline__ float leaky(float x) { return x > 0.f ? x : SLOPE * x; }
__device__ __forceinline__ ushort f2bf(float f) {
  uint32_t u = __float_as_uint(f);
  uint32_t r = (u + 0x7FFFu + ((u >> 16) & 1u)) >> 16;
  return (ushort)r;
}
__device__ __forceinline__ float bf2f(ushort u) { return __uint_as_float(((uint32_t)u) << 16); }

__device__ __forceinline__ int lower_bound_i(const int* __restrict__ arr, int n, int val) {
  int lo = 0, hi = n;
  while (lo < hi) { int mid = (lo + hi) >> 1; if (arr[mid] < val) lo = mid + 1; else hi = mid; }
  return lo;
}

// ---------------- conversions ----------------
__global__ __launch_bounds__(256) void cast_pad(const float* __restrict__ in, ushort* __restrict__ out) {
  size_t i = ((size_t)blockIdx.x * 256 + threadIdx.x) * 4;
  if (i >= (size_t)N_PAD * F_IN) return;
  int row = (int)(i >> 10);
  ushort4 o;
  if (row < N_NODES) {
    float4 v = *(const float4*)(in + i);
    o.x = f2bf(v.x); o.y = f2bf(v.y); o.z = f2bf(v.z); o.w = f2bf(v.w);
  } else {
    o.x = o.y = o.z = o.w = 0;
  }
  *(ushort4*)(out + i) = o;
}

// W [K=1024][N=1024] f32 -> Wt [N][K] bf16
__global__ __launch_bounds__(256) void convT_bf16(const float* __restrict__ W, ushort* __restrict__ Wt) {
  __shared__ float tile[32][33];
  const int k0 = blockIdx.x * 32, n0 = blockIdx.y * 32;
  const int tc = threadIdx.x & 31, tr = threadIdx.x >> 5;
#pragma unroll
  for (int q = 0; q < 4; ++q) {
    int r = tr + q * 8;
    tile[r][tc] = W[(size_t)(k0 + r) * F_IN + n0 + tc];
  }
  __syncthreads();
#pragma unroll
  for (int q = 0; q < 4; ++q) {
    int r = tr + q * 8;
    Wt[(size_t)(n0 + r) * F_IN + k0 + tc] = f2bf(tile[tc][r]);
  }
}

// ---------------- CSR build ----------------
__global__ void count_dst(const int* __restrict__ dst, int* __restrict__ cnt) {
  int i = blockIdx.x * blockDim.x + threadIdx.x;
  if (i < N_EDGES) atomicAdd(&cnt[dst[i]], 1);
}

__global__ void dinv_k(const int* __restrict__ cnt, float* __restrict__ dinv) {
  int i = blockIdx.x * blockDim.x + threadIdx.x;
  if (i < N_NODES) dinv[i] = rsqrtf((float)(cnt[i] + 1));
}

__global__ __launch_bounds__(1024) void scan_kernel(const int* __restrict__ cnt, int* __restrict__ rs, int n) {
  __shared__ int wsum[16];
  __shared__ int carry_s;
  const int t = threadIdx.x;
  const int lane = t & 63, wid = t >> 6;
  if (t == 0) { carry_s = 0; rs[0] = 0; }
  __syncthreads();
  for (int base = 0; base < n; base += 1024) {
    int i = base + t;
    int x = (i < n) ? cnt[i] : 0;
#pragma unroll
    for (int off = 1; off < 64; off <<= 1) {
      int v = __shfl_up(x, off, 64);
      if (lane >= off) x += v;
    }
    if (lane == 63) wsum[wid] = x;
    __syncthreads();
    if (wid == 0) {
      int s = (lane < 16) ? wsum[lane] : 0;
#pragma unroll
      for (int off = 1; off < 16; off <<= 1) {
        int v = __shfl_up(s, off, 64);
        if (lane >= off) s += v;
      }
      if (lane < 16) wsum[lane] = s;
    }
    __syncthreads();
    int inc = x + (wid > 0 ? wsum[wid - 1] : 0) + carry_s;
    if (i < n) rs[i + 1] = inc;
    __syncthreads();
    if (t == 1023) carry_s = inc;
    __syncthreads();
  }
}

__global__ void fill_csr(const int* __restrict__ src, const int* __restrict__ dst,
                         const int* __restrict__ rs, int* __restrict__ cursor,
                         int* __restrict__ esrc) {
  int i = blockIdx.x * blockDim.x + threadIdx.x;
  if (i < N_EDGES) {
    int d = dst[i];
    int pos = rs[d] + atomicAdd(&cursor[d], 1);
    esrc[pos] = src[i];
  }
}

// ---------------- bf16 MFMA GEMM ----------------
__global__ __launch_bounds__(256) void gemm_bf16(const ushort* __restrict__ A,
                                                 const ushort* __restrict__ Bt,
                                                 ushort* __restrict__ C) {
  __shared__ ushort lA[128 * 32];
  __shared__ ushort lB[128 * 32];
  const int t = threadIdx.x;
  const int lane = t & 63;
  const int w = t >> 6;
  const int wr = w >> 1, wc = w & 1;
  const int brow = blockIdx.x * 128;
  const int bcol = blockIdx.y * 128;

  const int si = w * 2;
  const int srow0 = si * 16 + (lane >> 2);
  const int srow1 = (si + 1) * 16 + (lane >> 2);
  const int skk = (lane & 3) * 8;
  const ushort* gA0 = A + (size_t)(brow + srow0) * F_IN + skk;
  const ushort* gA1 = A + (size_t)(brow + srow1) * F_IN + skk;
  const ushort* gB0 = Bt + (size_t)(bcol + srow0) * F_IN + skk;
  const ushort* gB1 = Bt + (size_t)(bcol + srow1) * F_IN + skk;
  ushort* lA0 = lA + si * 512;
  ushort* lA1 = lA + (si + 1) * 512;
  ushort* lB0 = lB + si * 512;
  ushort* lB1 = lB + (si + 1) * 512;

  f32x4 acc[4][4] = {};
  const int frow = lane & 15;
  const int fk = (lane >> 4) * 8;

  for (int k0 = 0; k0 < F_IN; k0 += 32) {
    __builtin_amdgcn_global_load_lds((const __attribute__((address_space(1))) void*)(gA0 + k0),
                                     (__attribute__((address_space(3))) void*)lA0, 16, 0, 0);
    __builtin_amdgcn_global_load_lds((const __attribute__((address_space(1))) void*)(gA1 + k0),
                                     (__attribute__((address_space(3))) void*)lA1, 16, 0, 0);
    __builtin_amdgcn_global_load_lds((const __attribute__((address_space(1))) void*)(gB0 + k0),
                                     (__attribute__((address_space(3))) void*)lB0, 16, 0, 0);
    __builtin_amdgcn_global_load_lds((const __attribute__((address_space(1))) void*)(gB1 + k0),
                                     (__attribute__((address_space(3))) void*)lB1, 16, 0, 0);
    __syncthreads();
    bf16x8 af[4], bfr[4];
#pragma unroll
    for (int m = 0; m < 4; ++m)
      af[m] = *(const bf16x8*)(lA + (wr * 64 + m * 16 + frow) * 32 + fk);
#pragma unroll
    for (int n = 0; n < 4; ++n)
      bfr[n] = *(const bf16x8*)(lB + (wc * 64 + n * 16 + frow) * 32 + fk);
#pragma unroll
    for (int m = 0; m < 4; ++m)
#pragma unroll
      for (int n = 0; n < 4; ++n)
        acc[m][n] = __builtin_amdgcn_mfma_f32_16x16x32_bf16(af[m], bfr[n], acc[m][n], 0, 0, 0);
    __syncthreads();
  }

#pragma unroll
  for (int m = 0; m < 4; ++m) {
    const int row0 = brow + wr * 64 + m * 16 + (lane >> 4) * 4;
#pragma unroll
    for (int n = 0; n < 4; ++n) {
      const int col = bcol + wc * 64 + n * 16 + (lane & 15);
#pragma unroll
      for (int j = 0; j < 4; ++j)
        C[(size_t)(row0 + j) * F_IN + col] = f2bf(acc[m][n][j]);
    }
  }
}

// ---------------- GCN aggregate ----------------
__global__ __launch_bounds__(256) void gcn_agg(const ushort* __restrict__ h,
                                               const int* __restrict__ rs,
                                               const int* __restrict__ esrc,
                                               const float* __restrict__ dinv,
                                               const float* __restrict__ bias,
                                               float* __restrict__ y) {
  const int node = blockIdx.x;
  const int t = threadIdx.x;
  const float din = dinv[node];
  ushort4 hv = ((const ushort4*)(h + (size_t)node * F_IN))[t];
  const float w0 = din * din;
  float a0 = bf2f(hv.x) * w0, a1 = bf2f(hv.y) * w0, a2 = bf2f(hv.z) * w0, a3 = bf2f(hv.w) * w0;
  const int e0 = rs[node], e1 = rs[node + 1];
  for (int e = e0; e < e1; ++e) {
    int s = esrc[e];
    float wgt = dinv[s] * din;
    ushort4 v = ((const ushort4*)(h + (size_t)s * F_IN))[t];
    a0 = fmaf(bf2f(v.x), wgt, a0); a1 = fmaf(bf2f(v.y), wgt, a1);
    a2 = fmaf(bf2f(v.z), wgt, a2); a3 = fmaf(bf2f(v.w), wgt, a3);
  }
  float4 bv = ((const float4*)bias)[t];
  float4 o;
  o.x = leaky(a0 + bv.x); o.y = leaky(a1 + bv.y);
  o.z = leaky(a2 + bv.z); o.w = leaky(a3 + bv.w);
  ((float4*)(y + (size_t)node * F_IN))[t] = o;
}

// ---------------- mean pool ----------------
__global__ __launch_bounds__(256) void pool_partial(const float* __restrict__ y,
                                                    const int* __restrict__ batch,
                                                    float* __restrict__ pool) {
  const int g = blockIdx.x;
  const int slice = blockIdx.y;
  const int t = threadIdx.x;
  int lo = lower_bound_i(batch, N_NODES, g);
  int hi = lower_bound_i(batch, N_NODES, g + 1);
  int cnt = hi - lo;
  int per = (cnt + 7) >> 3;
  int a = lo + slice * per;
  int b = min(a + per, hi);
  float s0 = 0.f, s1 = 0.f, s2 = 0.f, s3 = 0.f;
  for (int node = a; node < b; ++node) {
    float4 v = ((const float4*)(y + (size_t)node * F_IN))[t];
    s0 += v.x; s1 += v.y; s2 += v.z; s3 += v.w;
  }
  if (a < b) {
    atomicAdd(&pool[g * F_IN + 4 * t + 0], s0);
    atomicAdd(&pool[g * F_IN + 4 * t + 1], s1);
    atomicAdd(&pool[g * F_IN + 4 * t + 2], s2);
    atomicAdd(&pool[g * F_IN + 4 * t + 3], s3);
  }
}

// ---------------- FC ----------------
__global__ __launch_bounds__(128) void fc_kernel(const float* __restrict__ pool,
                                                 const int* __restrict__ batch,
                                                 const float* __restrict__ W,
                                                 const float* __restrict__ bias,
                                                 float* __restrict__ combined, int col_off) {
  const int g = blockIdx.x;
  const int t = threadIdx.x;
  __shared__ float p[F_IN];
  int lo = lower_bound_i(batch, N_NODES, g);
  int hi = lower_bound_i(batch, N_NODES, g + 1);
  float inv = 1.0f / (float)max(hi - lo, 1);
  for (int k = t; k < F_IN; k += 128) p[k] = pool[g * F_IN + k] * inv;
  __syncthreads();
  float acc = 0.f;
  for (int k = 0; k < F_IN; ++k) acc = fmaf(p[k], W[k * D_OUT + t], acc);
  combined[g * (6 * D_OUT) + col_off + t] = leaky(acc + bias[t]);
}

// ---------------- conv1d(k=1), all 4 branches, partial max over 64-chunk ----------------
__global__ __launch_bounds__(128) void conv_all(const float* __restrict__ m0, const float* __restrict__ m1,
                                                const float* __restrict__ m2, const float* __restrict__ m3,
                                                const float* __restrict__ W0, const float* __restrict__ W1,
                                                const float* __restrict__ W2, const float* __restrict__ W3,
                                                float* __restrict__ pmax) {
  const int ch = blockIdx.x;   // 32 chunks of 64
  const int g  = blockIdx.y;   // 16 graphs
  const int br = blockIdx.z;   // 4 branches
  const int t  = threadIdx.x;  // d
  const float* m = br == 0 ? m0 : br == 1 ? m1 : br == 2 ? m2 : m3;
  const float* W = br == 0 ? W0 : br == 1 ? W1 : br == 2 ? W2 : W3;
  __shared__ float ms[L_CHUNK * N_DESC];
  const float* mg = m + ((size_t)g * SEQ_L + (size_t)ch * L_CHUNK) * N_DESC;
  for (int i = t; i < L_CHUNK * N_DESC; i += 128) ms[i] = mg[i];
  float w[N_DESC];
#pragma unroll
  for (int k = 0; k < N_DESC; ++k) w[k] = W[k * D_OUT + t];
  __syncthreads();
  float best = -3.4e38f;
  for (int l = 0; l < L_CHUNK; ++l) {
    float acc = 0.f;
#pragma unroll
    for (int k = 0; k < N_DESC; ++k) acc = fmaf(ms[l * N_DESC + k], w[k], acc);
    best = fmaxf(best, acc);
  }
  pmax[((size_t)(br * N_GRAPHS + g) * N_CHUNKS + ch) * D_OUT + t] = best;
}

__global__ void conv_reduce(const float* __restrict__ pmax,
                            const float* __restrict__ b0, const float* __restrict__ b1,
                            const float* __restrict__ b2, const float* __restrict__ b3,
                            float* __restrict__ combined) {
  int i = blockIdx.x * blockDim.x + threadIdx.x;
  if (i >= 4 * N_GRAPHS * D_OUT) return;
  int br = i >> 11;
  int g = (i >> 7) & 15;
  int d = i & 127;
  const float* pm = pmax + ((size_t)(br * N_GRAPHS + g) * N_CHUNKS) * D_OUT + d;
  float best = -3.4e38f;
#pragma unroll
  for (int ch = 0; ch < N_CHUNKS; ++ch) best = fmaxf(best, pm[ch * D_OUT]);
  const float* bias = br == 0 ? b0 : br == 1 ? b1 : br == 2 ? b2 : b3;
  combined[g * (6 * D_OUT) + 2 * D_OUT + br * D_OUT + d] = leaky(best + bias[d]);
}

// ---------------- final linear ----------------
__global__ __launch_bounds__(256) void final_kernel(const float* __restrict__ combined,
                                                    const float* __restrict__ Wf,
                                                    const float* __restrict__ bf,
                                                    float* __restrict__ out) {
  const int g = blockIdx.x;
  const int t = threadIdx.x;
  float acc = 0.f;
  for (int k = t; k < 6 * D_OUT; k += 256) acc = fmaf(combined[g * 6 * D_OUT + k], Wf[k], acc);
  __shared__ float red[256];
  red[t] = acc;
  __syncthreads();
  for (int s = 128; s > 0; s >>= 1) {
    if (t < s) red[t] += red[t + s];
    __syncthreads();
  }
  if (t == 0) out[g] = red[0] + bf[0];
}

extern "C" void kernel_launch(void* const* d_in, const int* in_sizes, int n_in,
                              void* d_out, int out_size, void* d_ws, size_t ws_size,
                              hipStream_t stream) {
  const float* p1x  = (const float*)d_in[0];
  const int*   e1   = (const int*)d_in[1];
  const int*   bt1  = (const int*)d_in[2];
  const float* p2x  = (const float*)d_in[3];
  const int*   e2   = (const int*)d_in[4];
  const int*   bt2  = (const int*)d_in[5];
  const float* m1s  = (const float*)d_in[6];
  const float* m1f  = (const float*)d_in[7];
  const float* m2s  = (const float*)d_in[8];
  const float* m2f  = (const float*)d_in[9];
  const float* Wg1  = (const float*)d_in[10];
  const float* bg1  = (const float*)d_in[11];
  const float* Wfc1 = (const float*)d_in[12];
  const float* bfc1 = (const float*)d_in[13];
  const float* Wg2  = (const float*)d_in[14];
  const float* bg2  = (const float*)d_in[15];
  const float* Wfc2 = (const float*)d_in[16];
  const float* bfc2 = (const float*)d_in[17];
  const float* Wm1s = (const float*)d_in[18];
  const float* bm1s = (const float*)d_in[19];
  const float* Wm1f = (const float*)d_in[20];
  const float* bm1f = (const float*)d_in[21];
  const float* Wm2s = (const float*)d_in[22];
  const float* bm2s = (const float*)d_in[23];
  const float* Wm2f = (const float*)d_in[24];
  const float* bm2f = (const float*)d_in[25];
  const float* Wfin = (const float*)d_in[26];
  const float* bfin = (const float*)d_in[27];
  float* out = (float*)d_out;

  char* base = (char*)d_ws;
  size_t off = 0;
  auto alloc = [&](size_t bytes) -> void* {
    void* p = base + off;
    off = (off + bytes + 255) & ~(size_t)255;
    return p;
  };
  ushort* xbf   = (ushort*)alloc((size_t)N_PAD * F_IN * 2);
  ushort* wtbf  = (ushort*)alloc((size_t)F_IN * F_IN * 2);
  ushort* h     = (ushort*)alloc((size_t)N_PAD * F_IN * 2);
  float*  yb    = (float*)alloc((size_t)N_NODES * F_IN * 4);
  int*    cnt   = (int*)alloc((size_t)N_NODES * 4);
  float*  dinv  = (float*)alloc((size_t)N_NODES * 4);
  int*    rs    = (int*)alloc((size_t)(N_NODES + 1) * 4);
  int*    cursor= (int*)alloc((size_t)N_NODES * 4);
  int*    esrc  = (int*)alloc((size_t)N_EDGES * 4);
  float*  pool  = (float*)alloc((size_t)N_GRAPHS * F_IN * 4);
  float*  combined = (float*)alloc((size_t)N_GRAPHS * 6 * D_OUT * 4);
  float*  pmax  = (float*)alloc((size_t)4 * N_GRAPHS * N_CHUNKS * D_OUT * 4);
  (void)ws_size; (void)in_sizes; (void)n_in; (void)out_size;

  // descriptor conv branches (one fused launch, 2048 blocks)
  conv_all<<<dim3(N_CHUNKS, N_GRAPHS, 4), 128, 0, stream>>>(m1s, m1f, m2s, m2f,
                                                            Wm1s, Wm1f, Wm2s, Wm2f, pmax);
  conv_reduce<<<(4 * N_GRAPHS * D_OUT + 255) / 256, 256, 0, stream>>>(pmax, bm1s, bm1f, bm2s, bm2f, combined);

  const int cast_blocks = (int)(((size_t)N_PAD * F_IN / 4 + 255) / 256);

  for (int br = 0; br < 2; ++br) {
    const float* x   = br ? p2x : p1x;
    const int*   ei  = br ? e2 : e1;
    const int*   bt  = br ? bt2 : bt1;
    const float* Wg  = br ? Wg2 : Wg1;
    const float* bg  = br ? bg2 : bg1;
    const float* Wfc = br ? Wfc2 : Wfc1;
    const float* bfc = br ? bfc2 : bfc1;
    const int* srcv = ei;
    const int* dstv = ei + N_EDGES;

    hipMemsetAsync(cnt, 0, (size_t)N_NODES * 4, stream);
    hipMemsetAsync(cursor, 0, (size_t)N_NODES * 4, stream);
    hipMemsetAsync(pool, 0, (size_t)N_GRAPHS * F_IN * 4, stream);

    cast_pad<<<cast_blocks, 256, 0, stream>>>(x, xbf);
    convT_bf16<<<dim3(32, 32), 256, 0, stream>>>(Wg, wtbf);
    count_dst<<<(N_EDGES + 255) / 256, 256, 0, stream>>>(dstv, cnt);
    dinv_k<<<(N_NODES + 255) / 256, 256, 0, stream>>>(cnt, dinv);
    scan_kernel<<<1, 1024, 0, stream>>>(cnt, rs, N_NODES);
    fill_csr<<<(N_EDGES + 255) / 256, 256, 0, stream>>>(srcv, dstv, rs, cursor, esrc);

    gemm_bf16<<<dim3(N_PAD / 128, F_IN / 128), 256, 0, stream>>>(xbf, wtbf, h);
    gcn_agg<<<N_NODES, 256, 0, stream>>>(h, rs, esrc, dinv, bg, yb);
    pool_partial<<<dim3(N_GRAPHS, 8), 256, 0, stream>>>(yb, bt, pool);
    fc_kernel<<<N_GRAPHS, 128, 0, stream>>>(pool, bt, Wfc, bfc, combined, br * D_OUT);
  }

  final_kernel<<<N_GRAPHS, 256, 0, stream>>>(combined, Wfin, bfin, out);
}

// Round 4
// 588.215 us; speedup vs baseline: 3.2945x; 1.1215x over previous
//
#include <hip/hip_runtime.h>
#include <cstdint>
#include <cstddef>

constexpr int N_NODES  = 20000;
constexpr int N_PAD    = 20096;   // 157 * 128
constexpr int N_EDGES  = 160000;
constexpr int N_GRAPHS = 16;
constexpr int SEQ_L    = 2048;
constexpr int F_IN     = 1024;
constexpr int D_OUT    = 128;
constexpr int N_DESC   = 80;
constexpr int K_PAD    = 104;     // 80 padded to 96 for MFMA k-steps, 104 stride for banks
constexpr int N_CCH    = 16;      // L-chunks of 128
constexpr float SLOPE  = 0.01f;

typedef short bf16x8 __attribute__((ext_vector_type(8)));
typedef float f32x4  __attribute__((ext_vector_type(4)));

__device__ __forceinline__ float leaky(float x) { return x > 0.f ? x : SLOPE * x; }
__device__ __forceinline__ ushort f2bf(float f) {
  uint32_t u = __float_as_uint(f);
  uint32_t r = (u + 0x7FFFu + ((u >> 16) & 1u)) >> 16;
  return (ushort)r;
}
__device__ __forceinline__ float bf2f(ushort u) { return __uint_as_float(((uint32_t)u) << 16); }

__device__ __forceinline__ int lower_bound_i(const int* __restrict__ arr, int n, int val) {
  int lo = 0, hi = n;
  while (lo < hi) { int mid = (lo + hi) >> 1; if (arr[mid] < val) lo = mid + 1; else hi = mid; }
  return lo;
}

// ---------------- conversions ----------------
__global__ __launch_bounds__(256) void cast_pad(const float* __restrict__ in, ushort* __restrict__ out) {
  size_t i = ((size_t)blockIdx.x * 256 + threadIdx.x) * 4;
  if (i >= (size_t)N_PAD * F_IN) return;
  int row = (int)(i >> 10);
  ushort4 o;
  if (row < N_NODES) {
    float4 v = *(const float4*)(in + i);
    o.x = f2bf(v.x); o.y = f2bf(v.y); o.z = f2bf(v.z); o.w = f2bf(v.w);
  } else {
    o.x = o.y = o.z = o.w = 0;
  }
  *(ushort4*)(out + i) = o;
}

// W [K=1024][N=1024] f32 -> Wt [N][K] bf16
__global__ __launch_bounds__(256) void convT_bf16(const float* __restrict__ W, ushort* __restrict__ Wt) {
  __shared__ float tile[32][33];
  const int k0 = blockIdx.x * 32, n0 = blockIdx.y * 32;
  const int tc = threadIdx.x & 31, tr = threadIdx.x >> 5;
#pragma unroll
  for (int q = 0; q < 4; ++q) {
    int r = tr + q * 8;
    tile[r][tc] = W[(size_t)(k0 + r) * F_IN + n0 + tc];
  }
  __syncthreads();
#pragma unroll
  for (int q = 0; q < 4; ++q) {
    int r = tr + q * 8;
    Wt[(size_t)(n0 + r) * F_IN + k0 + tc] = f2bf(tile[tc][r]);
  }
}

// conv weights: W [80][128] f32 -> Wt [br][128 col][K_PAD k] bf16 (zero-padded k>=80)
__global__ __launch_bounds__(256) void conv_w_prep(const float* __restrict__ W0, const float* __restrict__ W1,
                                                   const float* __restrict__ W2, const float* __restrict__ W3,
                                                   ushort* __restrict__ Wt) {
  const int br = blockIdx.y;
  const float* W = br == 0 ? W0 : br == 1 ? W1 : br == 2 ? W2 : W3;
  int i = blockIdx.x * 256 + threadIdx.x;
  if (i >= D_OUT * K_PAD) return;
  int col = i / K_PAD, k = i - col * K_PAD;
  Wt[(size_t)br * D_OUT * K_PAD + i] = (k < N_DESC) ? f2bf(W[k * D_OUT + col]) : (ushort)0;
}

// ---------------- CSR build ----------------
__global__ void count_dst(const int* __restrict__ dst, int* __restrict__ cnt) {
  int i = blockIdx.x * blockDim.x + threadIdx.x;
  if (i < N_EDGES) atomicAdd(&cnt[dst[i]], 1);
}

__global__ void dinv_k(const int* __restrict__ cnt, float* __restrict__ dinv) {
  int i = blockIdx.x * blockDim.x + threadIdx.x;
  if (i < N_NODES) dinv[i] = rsqrtf((float)(cnt[i] + 1));
}

__global__ __launch_bounds__(1024) void scan_kernel(const int* __restrict__ cnt, int* __restrict__ rs, int n) {
  __shared__ int wsum[16];
  __shared__ int carry_s;
  const int t = threadIdx.x;
  const int lane = t & 63, wid = t >> 6;
  if (t == 0) { carry_s = 0; rs[0] = 0; }
  __syncthreads();
  for (int base = 0; base < n; base += 1024) {
    int i = base + t;
    int x = (i < n) ? cnt[i] : 0;
#pragma unroll
    for (int off = 1; off < 64; off <<= 1) {
      int v = __shfl_up(x, off, 64);
      if (lane >= off) x += v;
    }
    if (lane == 63) wsum[wid] = x;
    __syncthreads();
    if (wid == 0) {
      int s = (lane < 16) ? wsum[lane] : 0;
#pragma unroll
      for (int off = 1; off < 16; off <<= 1) {
        int v = __shfl_up(s, off, 64);
        if (lane >= off) s += v;
      }
      if (lane < 16) wsum[lane] = s;
    }
    __syncthreads();
    int inc = x + (wid > 0 ? wsum[wid - 1] : 0) + carry_s;
    if (i < n) rs[i + 1] = inc;
    __syncthreads();
    if (t == 1023) carry_s = inc;
    __syncthreads();
  }
}

__global__ void fill_csr(const int* __restrict__ src, const int* __restrict__ dst,
                         const int* __restrict__ rs, int* __restrict__ cursor,
                         int* __restrict__ esrc) {
  int i = blockIdx.x * blockDim.x + threadIdx.x;
  if (i < N_EDGES) {
    int d = dst[i];
    int pos = rs[d] + atomicAdd(&cursor[d], 1);
    esrc[pos] = src[i];
  }
}

// ---------------- bf16 MFMA GEMM ----------------
__global__ __launch_bounds__(256) void gemm_bf16(const ushort* __restrict__ A,
                                                 const ushort* __restrict__ Bt,
                                                 ushort* __restrict__ C) {
  __shared__ ushort lA[128 * 32];
  __shared__ ushort lB[128 * 32];
  const int t = threadIdx.x;
  const int lane = t & 63;
  const int w = t >> 6;
  const int wr = w >> 1, wc = w & 1;
  const int brow = blockIdx.x * 128;
  const int bcol = blockIdx.y * 128;

  const int si = w * 2;
  const int srow0 = si * 16 + (lane >> 2);
  const int srow1 = (si + 1) * 16 + (lane >> 2);
  const int skk = (lane & 3) * 8;
  const ushort* gA0 = A + (size_t)(brow + srow0) * F_IN + skk;
  const ushort* gA1 = A + (size_t)(brow + srow1) * F_IN + skk;
  const ushort* gB0 = Bt + (size_t)(bcol + srow0) * F_IN + skk;
  const ushort* gB1 = Bt + (size_t)(bcol + srow1) * F_IN + skk;
  ushort* lA0 = lA + si * 512;
  ushort* lA1 = lA + (si + 1) * 512;
  ushort* lB0 = lB + si * 512;
  ushort* lB1 = lB + (si + 1) * 512;

  f32x4 acc[4][4] = {};
  const int frow = lane & 15;
  const int fk = (lane >> 4) * 8;

  for (int k0 = 0; k0 < F_IN; k0 += 32) {
    __builtin_amdgcn_global_load_lds((const __attribute__((address_space(1))) void*)(gA0 + k0),
                                     (__attribute__((address_space(3))) void*)lA0, 16, 0, 0);
    __builtin_amdgcn_global_load_lds((const __attribute__((address_space(1))) void*)(gA1 + k0),
                                     (__attribute__((address_space(3))) void*)lA1, 16, 0, 0);
    __builtin_amdgcn_global_load_lds((const __attribute__((address_space(1))) void*)(gB0 + k0),
                                     (__attribute__((address_space(3))) void*)lB0, 16, 0, 0);
    __builtin_amdgcn_global_load_lds((const __attribute__((address_space(1))) void*)(gB1 + k0),
                                     (__attribute__((address_space(3))) void*)lB1, 16, 0, 0);
    __syncthreads();
    bf16x8 af[4], bfr[4];
#pragma unroll
    for (int m = 0; m < 4; ++m)
      af[m] = *(const bf16x8*)(lA + (wr * 64 + m * 16 + frow) * 32 + fk);
#pragma unroll
    for (int n = 0; n < 4; ++n)
      bfr[n] = *(const bf16x8*)(lB + (wc * 64 + n * 16 + frow) * 32 + fk);
#pragma unroll
    for (int m = 0; m < 4; ++m)
#pragma unroll
      for (int n = 0; n < 4; ++n)
        acc[m][n] = __builtin_amdgcn_mfma_f32_16x16x32_bf16(af[m], bfr[n], acc[m][n], 0, 0, 0);
    __syncthreads();
  }

#pragma unroll
  for (int m = 0; m < 4; ++m) {
    const int row0 = brow + wr * 64 + m * 16 + (lane >> 4) * 4;
#pragma unroll
    for (int n = 0; n < 4; ++n) {
      const int col = bcol + wc * 64 + n * 16 + (lane & 15);
#pragma unroll
      for (int j = 0; j < 4; ++j)
        C[(size_t)(row0 + j) * F_IN + col] = f2bf(acc[m][n][j]);
    }
  }
}

// ---------------- GCN aggregate (bf16 h in, bf16 y out) ----------------
__global__ __launch_bounds__(256) void gcn_agg(const ushort* __restrict__ h,
                                               const int* __restrict__ rs,
                                               const int* __restrict__ esrc,
                                               const float* __restrict__ dinv,
                                               const float* __restrict__ bias,
                                               ushort* __restrict__ y) {
  const int node = blockIdx.x;
  const int t = threadIdx.x;
  const float din = dinv[node];
  ushort4 hv = ((const ushort4*)(h + (size_t)node * F_IN))[t];
  const float w0 = din * din;
  float a0 = bf2f(hv.x) * w0, a1 = bf2f(hv.y) * w0, a2 = bf2f(hv.z) * w0, a3 = bf2f(hv.w) * w0;
  const int e0 = rs[node], e1 = rs[node + 1];
  for (int e = e0; e < e1; ++e) {
    int s = esrc[e];
    float wgt = dinv[s] * din;
    ushort4 v = ((const ushort4*)(h + (size_t)s * F_IN))[t];
    a0 = fmaf(bf2f(v.x), wgt, a0); a1 = fmaf(bf2f(v.y), wgt, a1);
    a2 = fmaf(bf2f(v.z), wgt, a2); a3 = fmaf(bf2f(v.w), wgt, a3);
  }
  float4 bv = ((const float4*)bias)[t];
  ushort4 o;
  o.x = f2bf(leaky(a0 + bv.x)); o.y = f2bf(leaky(a1 + bv.y));
  o.z = f2bf(leaky(a2 + bv.z)); o.w = f2bf(leaky(a3 + bv.w));
  ((ushort4*)(y + (size_t)node * F_IN))[t] = o;
}

// ---------------- mean pool (bf16 y) ----------------
__global__ __launch_bounds__(256) void pool_partial(const ushort* __restrict__ y,
                                                    const int* __restrict__ batch,
                                                    float* __restrict__ pool) {
  const int g = blockIdx.x;
  const int slice = blockIdx.y;
  const int t = threadIdx.x;
  int lo = lower_bound_i(batch, N_NODES, g);
  int hi = lower_bound_i(batch, N_NODES, g + 1);
  int cnt = hi - lo;
  int per = (cnt + 7) >> 3;
  int a = lo + slice * per;
  int b = min(a + per, hi);
  float s0 = 0.f, s1 = 0.f, s2 = 0.f, s3 = 0.f;
  for (int node = a; node < b; ++node) {
    ushort4 v = ((const ushort4*)(y + (size_t)node * F_IN))[t];
    s0 += bf2f(v.x); s1 += bf2f(v.y); s2 += bf2f(v.z); s3 += bf2f(v.w);
  }
  if (a < b) {
    atomicAdd(&pool[g * F_IN + 4 * t + 0], s0);
    atomicAdd(&pool[g * F_IN + 4 * t + 1], s1);
    atomicAdd(&pool[g * F_IN + 4 * t + 2], s2);
    atomicAdd(&pool[g * F_IN + 4 * t + 3], s3);
  }
}

// ---------------- FC ----------------
__global__ __launch_bounds__(128) void fc_kernel(const float* __restrict__ pool,
                                                 const int* __restrict__ batch,
                                                 const float* __restrict__ W,
                                                 const float* __restrict__ bias,
                                                 float* __restrict__ combined, int col_off) {
  const int g = blockIdx.x;
  const int t = threadIdx.x;
  __shared__ float p[F_IN];
  int lo = lower_bound_i(batch, N_NODES, g);
  int hi = lower_bound_i(batch, N_NODES, g + 1);
  float inv = 1.0f / (float)max(hi - lo, 1);
  for (int k = t; k < F_IN; k += 128) p[k] = pool[g * F_IN + k] * inv;
  __syncthreads();
  float acc = 0.f;
  for (int k = 0; k < F_IN; ++k) acc = fmaf(p[k], W[k * D_OUT + t], acc);
  combined[g * (6 * D_OUT) + col_off + t] = leaky(acc + bias[t]);
}

// ---------------- conv1d(k=1) via MFMA: [128 L-rows x 80] @ [80 x 128], max over rows ----------------
__global__ __launch_bounds__(256) void conv_mfma(const float* __restrict__ m0, const float* __restrict__ m1,
                                                 const float* __restrict__ m2, const float* __restrict__ m3,
                                                 const ushort* __restrict__ Wt,
                                                 float* __restrict__ pmax) {
  const int ch = blockIdx.x;   // 16 chunks of 128 L-rows
  const int g  = blockIdx.y;   // 16 graphs
  const int br = blockIdx.z;   // 4 branches
  const int t  = threadIdx.x;
  const int lane = t & 63, w = t >> 6;
  const float* m = br == 0 ? m0 : br == 1 ? m1 : br == 2 ? m2 : m3;

  __shared__ __align__(16) ushort lA[128 * K_PAD];
  __shared__ __align__(16) ushort lB[D_OUT * K_PAD];
  __shared__ float smax[4 * D_OUT];

  // stage B (pre-cast, padded, [col][K_PAD]) via global_load_lds: 26624 B = 26 x 1KB
  const ushort* wsrc = Wt + (size_t)br * D_OUT * K_PAD;
  for (int i = w; i < 26; i += 4)
    __builtin_amdgcn_global_load_lds((const __attribute__((address_space(1))) void*)(wsrc + i * 512 + lane * 8),
                                     (__attribute__((address_space(3))) void*)(lB + i * 512), 16, 0, 0);

  // stage A: 128 rows x 80 f32 -> bf16, row stride K_PAD
  const float4* mg4 = (const float4*)(m + ((size_t)g * SEQ_L + (size_t)ch * 128) * N_DESC);
#pragma unroll
  for (int j = 0; j < 10; ++j) {
    int fi = t + j * 256;             // 0..2559 over 128 rows x 20 float4
    int row = fi / 20, off = fi - row * 20;
    float4 v = mg4[fi];
    ushort4 o;
    o.x = f2bf(v.x); o.y = f2bf(v.y); o.z = f2bf(v.z); o.w = f2bf(v.w);
    *(ushort4*)(lA + row * K_PAD + off * 4) = o;
  }
  if (t < 128) {   // zero-pad k in [80,96)
    ushort4 z = {0, 0, 0, 0};
    *(ushort4*)(lA + t * K_PAD + 80) = z;
    *(ushort4*)(lA + t * K_PAD + 84) = z;
    *(ushort4*)(lA + t * K_PAD + 88) = z;
    *(ushort4*)(lA + t * K_PAD + 92) = z;
  }
  __syncthreads();

  const int frow = lane & 15, fk = (lane >> 4) * 8;
  f32x4 acc[2][8] = {};
#pragma unroll
  for (int ks = 0; ks < 3; ++ks) {
    bf16x8 af[2], bfr[8];
#pragma unroll
    for (int mm = 0; mm < 2; ++mm)
      af[mm] = *(const bf16x8*)(lA + (w * 32 + mm * 16 + frow) * K_PAD + ks * 32 + fk);
#pragma unroll
    for (int n = 0; n < 8; ++n)
      bfr[n] = *(const bf16x8*)(lB + (n * 16 + frow) * K_PAD + ks * 32 + fk);
#pragma unroll
    for (int mm = 0; mm < 2; ++mm)
#pragma unroll
      for (int n = 0; n < 8; ++n)
        acc[mm][n] = __builtin_amdgcn_mfma_f32_16x16x32_bf16(af[mm], bfr[n], acc[mm][n], 0, 0, 0);
  }

  // max over the 32 rows this wave owns: lane holds rows (lane>>4)*4+j of each 16-row frag
#pragma unroll
  for (int n = 0; n < 8; ++n) {
    float v = acc[0][n][0];
#pragma unroll
    for (int j = 1; j < 4; ++j) v = fmaxf(v, acc[0][n][j]);
#pragma unroll
    for (int j = 0; j < 4; ++j) v = fmaxf(v, acc[1][n][j]);
    v = fmaxf(v, __shfl_xor(v, 16, 64));
    v = fmaxf(v, __shfl_xor(v, 32, 64));
    if (lane < 16) smax[w * D_OUT + n * 16 + lane] = v;
  }
  __syncthreads();
  if (t < D_OUT) {
    float v = fmaxf(fmaxf(smax[t], smax[D_OUT + t]),
                    fmaxf(smax[2 * D_OUT + t], smax[3 * D_OUT + t]));
    pmax[(((size_t)br * N_GRAPHS + g) * N_CCH + ch) * D_OUT + t] = v;
  }
}

__global__ void conv_reduce(const float* __restrict__ pmax,
                            const float* __restrict__ b0, const float* __restrict__ b1,
                            const float* __restrict__ b2, const float* __restrict__ b3,
                            float* __restrict__ combined) {
  int i = blockIdx.x * blockDim.x + threadIdx.x;
  if (i >= 4 * N_GRAPHS * D_OUT) return;
  int br = i >> 11;
  int g = (i >> 7) & 15;
  int d = i & 127;
  const float* pm = pmax + ((size_t)(br * N_GRAPHS + g) * N_CCH) * D_OUT + d;
  float best = -3.4e38f;
#pragma unroll
  for (int ch = 0; ch < N_CCH; ++ch) best = fmaxf(best, pm[ch * D_OUT]);
  const float* bias = br == 0 ? b0 : br == 1 ? b1 : br == 2 ? b2 : b3;
  combined[g * (6 * D_OUT) + 2 * D_OUT + br * D_OUT + d] = leaky(best + bias[d]);
}

// ---------------- final linear ----------------
__global__ __launch_bounds__(256) void final_kernel(const float* __restrict__ combined,
                                                    const float* __restrict__ Wf,
                                                    const float* __restrict__ bf,
                                                    float* __restrict__ out) {
  const int g = blockIdx.x;
  const int t = threadIdx.x;
  float acc = 0.f;
  for (int k = t; k < 6 * D_OUT; k += 256) acc = fmaf(combined[g * 6 * D_OUT + k], Wf[k], acc);
  __shared__ float red[256];
  red[t] = acc;
  __syncthreads();
  for (int s = 128; s > 0; s >>= 1) {
    if (t < s) red[t] += red[t + s];
    __syncthreads();
  }
  if (t == 0) out[g] = red[0] + bf[0];
}

extern "C" void kernel_launch(void* const* d_in, const int* in_sizes, int n_in,
                              void* d_out, int out_size, void* d_ws, size_t ws_size,
                              hipStream_t stream) {
  const float* p1x  = (const float*)d_in[0];
  const int*   e1   = (const int*)d_in[1];
  const int*   bt1  = (const int*)d_in[2];
  const float* p2x  = (const float*)d_in[3];
  const int*   e2   = (const int*)d_in[4];
  const int*   bt2  = (const int*)d_in[5];
  const float* m1s  = (const float*)d_in[6];
  const float* m1f  = (const float*)d_in[7];
  const float* m2s  = (const float*)d_in[8];
  const float* m2f  = (const float*)d_in[9];
  const float* Wg1  = (const float*)d_in[10];
  const float* bg1  = (const float*)d_in[11];
  const float* Wfc1 = (const float*)d_in[12];
  const float* bfc1 = (const float*)d_in[13];
  const float* Wg2  = (const float*)d_in[14];
  const float* bg2  = (const float*)d_in[15];
  const float* Wfc2 = (const float*)d_in[16];
  const float* bfc2 = (const float*)d_in[17];
  const float* Wm1s = (const float*)d_in[18];
  const float* bm1s = (const float*)d_in[19];
  const float* Wm1f = (const float*)d_in[20];
  const float* bm1f = (const float*)d_in[21];
  const float* Wm2s = (const float*)d_in[22];
  const float* bm2s = (const float*)d_in[23];
  const float* Wm2f = (const float*)d_in[24];
  const float* bm2f = (const float*)d_in[25];
  const float* Wfin = (const float*)d_in[26];
  const float* bfin = (const float*)d_in[27];
  float* out = (float*)d_out;

  char* base = (char*)d_ws;
  size_t off = 0;
  auto alloc = [&](size_t bytes) -> void* {
    void* p = base + off;
    off = (off + bytes + 255) & ~(size_t)255;
    return p;
  };
  ushort* xbf    = (ushort*)alloc((size_t)N_PAD * F_IN * 2);
  ushort* wtbf   = (ushort*)alloc((size_t)F_IN * F_IN * 2);
  ushort* h      = (ushort*)alloc((size_t)N_PAD * F_IN * 2);
  ushort* ybf    = (ushort*)alloc((size_t)N_NODES * F_IN * 2);
  ushort* wtconv = (ushort*)alloc((size_t)4 * D_OUT * K_PAD * 2);
  int*    cnt    = (int*)alloc((size_t)N_NODES * 4);
  float*  dinv   = (float*)alloc((size_t)N_NODES * 4);
  int*    rs     = (int*)alloc((size_t)(N_NODES + 1) * 4);
  int*    cursor = (int*)alloc((size_t)N_NODES * 4);
  int*    esrc   = (int*)alloc((size_t)N_EDGES * 4);
  float*  pool   = (float*)alloc((size_t)N_GRAPHS * F_IN * 4);
  float*  combined = (float*)alloc((size_t)N_GRAPHS * 6 * D_OUT * 4);
  float*  pmax   = (float*)alloc((size_t)4 * N_GRAPHS * N_CCH * D_OUT * 4);
  (void)ws_size; (void)in_sizes; (void)n_in; (void)out_size;

  // descriptor conv branches: weight prep + one fused MFMA launch
  conv_w_prep<<<dim3((D_OUT * K_PAD + 255) / 256, 4), 256, 0, stream>>>(Wm1s, Wm1f, Wm2s, Wm2f, wtconv);
  conv_mfma<<<dim3(N_CCH, N_GRAPHS, 4), 256, 0, stream>>>(m1s, m1f, m2s, m2f, wtconv, pmax);
  conv_reduce<<<(4 * N_GRAPHS * D_OUT + 255) / 256, 256, 0, stream>>>(pmax, bm1s, bm1f, bm2s, bm2f, combined);

  const int cast_blocks = (int)(((size_t)N_PAD * F_IN / 4 + 255) / 256);

  for (int br = 0; br < 2; ++br) {
    const float* x   = br ? p2x : p1x;
    const int*   ei  = br ? e2 : e1;
    const int*   bt  = br ? bt2 : bt1;
    const float* Wg  = br ? Wg2 : Wg1;
    const float* bg  = br ? bg2 : bg1;
    const float* Wfc = br ? Wfc2 : Wfc1;
    const float* bfc = br ? bfc2 : bfc1;
    const int* srcv = ei;
    const int* dstv = ei + N_EDGES;

    hipMemsetAsync(cnt, 0, (size_t)N_NODES * 4, stream);
    hipMemsetAsync(cursor, 0, (size_t)N_NODES * 4, stream);
    hipMemsetAsync(pool, 0, (size_t)N_GRAPHS * F_IN * 4, stream);

    cast_pad<<<cast_blocks, 256, 0, stream>>>(x, xbf);
    convT_bf16<<<dim3(32, 32), 256, 0, stream>>>(Wg, wtbf);
    count_dst<<<(N_EDGES + 255) / 256, 256, 0, stream>>>(dstv, cnt);
    dinv_k<<<(N_NODES + 255) / 256, 256, 0, stream>>>(cnt, dinv);
    scan_kernel<<<1, 1024, 0, stream>>>(cnt, rs, N_NODES);
    fill_csr<<<(N_EDGES + 255) / 256, 256, 0, stream>>>(srcv, dstv, rs, cursor, esrc);

    gemm_bf16<<<dim3(N_PAD / 128, F_IN / 128), 256, 0, stream>>>(xbf, wtbf, h);
    gcn_agg<<<N_NODES, 256, 0, stream>>>(h, rs, esrc, dinv, bg, ybf);
    pool_partial<<<dim3(N_GRAPHS, 8), 256, 0, stream>>>(ybf, bt, pool);
    fc_kernel<<<N_GRAPHS, 128, 0, stream>>>(pool, bt, Wfc, bfc, combined, br * D_OUT);
  }

  final_kernel<<<N_GRAPHS, 256, 0, stream>>>(combined, Wfin, bfin, out);
}

// Round 5
// 445.745 us; speedup vs baseline: 4.3475x; 1.3196x over previous
//
#include <hip/hip_runtime.h>
#include <cstdint>
#include <cstddef>

constexpr int N_NODES  = 20000;
constexpr int N_PAD    = 20096;   // 157 * 128
constexpr int N_EDGES  = 160000;
constexpr int N_GRAPHS = 16;
constexpr int SEQ_L    = 2048;
constexpr int F_IN     = 1024;
constexpr int D_OUT    = 128;
constexpr int N_DESC   = 80;
constexpr int K_PAD    = 104;     // conv: 80 padded to 96 for MFMA, 104 stride for banks
constexpr int N_CCH    = 16;      // conv: L-chunks of 128
constexpr int ROWB     = N_PAD / 128;      // 157
constexpr int NWG_GEMM = 2 * ROWB * 8;     // 2512, divisible by 8
constexpr float SLOPE  = 0.01f;

typedef short bf16x8 __attribute__((ext_vector_type(8)));
typedef float f32x4  __attribute__((ext_vector_type(4)));

__device__ __forceinline__ float leaky(float x) { return x > 0.f ? x : SLOPE * x; }
__device__ __forceinline__ ushort f2bf(float f) {
  uint32_t u = __float_as_uint(f);
  uint32_t r = (u + 0x7FFFu + ((u >> 16) & 1u)) >> 16;
  return (ushort)r;
}
__device__ __forceinline__ float bf2f(ushort u) { return __uint_as_float(((uint32_t)u) << 16); }

__device__ __forceinline__ int lower_bound_i(const int* __restrict__ arr, int n, int val) {
  int lo = 0, hi = n;
  while (lo < hi) { int mid = (lo + hi) >> 1; if (arr[mid] < val) lo = mid + 1; else hi = mid; }
  return lo;
}

// ---------------- conversions (both branches, z = branch) ----------------
__global__ __launch_bounds__(256) void cast_pad2(const float* __restrict__ x0, const float* __restrict__ x1,
                                                 ushort* __restrict__ out) {
  const int z = blockIdx.y;
  const float* in = z ? x1 : x0;
  size_t i = ((size_t)blockIdx.x * 256 + threadIdx.x) * 4;
  if (i >= (size_t)N_PAD * F_IN) return;
  int row = (int)(i >> 10);
  ushort4 o;
  if (row < N_NODES) {
    float4 v = *(const float4*)(in + i);
    o.x = f2bf(v.x); o.y = f2bf(v.y); o.z = f2bf(v.z); o.w = f2bf(v.w);
  } else {
    o.x = o.y = o.z = o.w = 0;
  }
  *(ushort4*)(out + (size_t)z * N_PAD * F_IN + i) = o;
}

// W [K=1024][N=1024] f32 -> Wt [N][K] bf16, both branches
__global__ __launch_bounds__(256) void convT2(const float* __restrict__ W0, const float* __restrict__ W1,
                                              ushort* __restrict__ Wt) {
  const int z = blockIdx.z;
  const float* W = z ? W1 : W0;
  __shared__ float tile[32][33];
  const int k0 = blockIdx.x * 32, n0 = blockIdx.y * 32;
  const int tc = threadIdx.x & 31, tr = threadIdx.x >> 5;
#pragma unroll
  for (int q = 0; q < 4; ++q) {
    int r = tr + q * 8;
    tile[r][tc] = W[(size_t)(k0 + r) * F_IN + n0 + tc];
  }
  __syncthreads();
  ushort* Wz = Wt + (size_t)z * F_IN * F_IN;
#pragma unroll
  for (int q = 0; q < 4; ++q) {
    int r = tr + q * 8;
    Wz[(size_t)(n0 + r) * F_IN + k0 + tc] = f2bf(tile[tc][r]);
  }
}

// conv weights: W [80][128] f32 -> Wt [br][128 col][K_PAD k] bf16 (zero-padded k>=80)
__global__ __launch_bounds__(256) void conv_w_prep(const float* __restrict__ W0, const float* __restrict__ W1,
                                                   const float* __restrict__ W2, const float* __restrict__ W3,
                                                   ushort* __restrict__ Wt) {
  const int br = blockIdx.y;
  const float* W = br == 0 ? W0 : br == 1 ? W1 : br == 2 ? W2 : W3;
  int i = blockIdx.x * 256 + threadIdx.x;
  if (i >= D_OUT * K_PAD) return;
  int col = i / K_PAD, k = i - col * K_PAD;
  Wt[(size_t)br * D_OUT * K_PAD + i] = (k < N_DESC) ? f2bf(W[k * D_OUT + col]) : (ushort)0;
}

// ---------------- CSR build (both branches) ----------------
__global__ void count_dst2(const int* __restrict__ e0, const int* __restrict__ e1,
                           int* __restrict__ cnt) {
  const int z = blockIdx.y;
  const int* dst = (z ? e1 : e0) + N_EDGES;
  int i = blockIdx.x * blockDim.x + threadIdx.x;
  if (i < N_EDGES) atomicAdd(&cnt[z * N_NODES + dst[i]], 1);
}

// one block per branch: dinv + exclusive scan of cnt -> rs
__global__ __launch_bounds__(1024) void scan2(const int* __restrict__ cnt, int* __restrict__ rs,
                                              float* __restrict__ dinv) {
  const int z = blockIdx.x;
  const int* c = cnt + (size_t)z * N_NODES;
  int* r = rs + (size_t)z * (N_NODES + 1);
  float* dv = dinv + (size_t)z * N_NODES;
  const int t = threadIdx.x;
  for (int i = t; i < N_NODES; i += 1024) dv[i] = rsqrtf((float)(c[i] + 1));  // +1 self loop
  __shared__ int wsum[16];
  __shared__ int carry_s;
  const int lane = t & 63, wid = t >> 6;
  if (t == 0) { carry_s = 0; r[0] = 0; }
  __syncthreads();
  for (int base = 0; base < N_NODES; base += 1024) {
    int i = base + t;
    int x = (i < N_NODES) ? c[i] : 0;
#pragma unroll
    for (int off = 1; off < 64; off <<= 1) {
      int v = __shfl_up(x, off, 64);
      if (lane >= off) x += v;
    }
    if (lane == 63) wsum[wid] = x;
    __syncthreads();
    if (wid == 0) {
      int s = (lane < 16) ? wsum[lane] : 0;
#pragma unroll
      for (int off = 1; off < 16; off <<= 1) {
        int v = __shfl_up(s, off, 64);
        if (lane >= off) s += v;
      }
      if (lane < 16) wsum[lane] = s;
    }
    __syncthreads();
    int inc = x + (wid > 0 ? wsum[wid - 1] : 0) + carry_s;
    if (i < N_NODES) r[i + 1] = inc;
    __syncthreads();
    if (t == 1023) carry_s = inc;
    __syncthreads();
  }
}

__global__ void fill_csr2(const int* __restrict__ e0, const int* __restrict__ e1,
                          const int* __restrict__ rs, int* __restrict__ cursor,
                          int* __restrict__ esrc) {
  const int z = blockIdx.y;
  const int* src = z ? e1 : e0;
  const int* dst = src + N_EDGES;
  int i = blockIdx.x * blockDim.x + threadIdx.x;
  if (i < N_EDGES) {
    int d = dst[i];
    int pos = rs[(size_t)z * (N_NODES + 1) + d] + atomicAdd(&cursor[z * N_NODES + d], 1);
    esrc[(size_t)z * N_EDGES + pos] = src[i];
  }
}

// ---------------- bf16 MFMA GEMM, both branches, XCD-swizzled flat grid ----------------
__global__ __launch_bounds__(256) void gemm2(const ushort* __restrict__ A,
                                             const ushort* __restrict__ Bt,
                                             ushort* __restrict__ C) {
  // bijective XCD swizzle (m204): nwg=2512, q=314; XCD k owns contiguous swz range
  const int bid = blockIdx.x;
  const int swz = (bid & 7) * (NWG_GEMM / 8) + (bid >> 3);
  const int br  = swz / (ROWB * 8);
  const int rem = swz - br * (ROWB * 8);
  const int rowb = rem >> 3, colb = rem & 7;

  const ushort* Az = A + (size_t)br * N_PAD * F_IN;
  const ushort* Bz = Bt + (size_t)br * F_IN * F_IN;
  ushort* Cz = C + (size_t)br * N_PAD * F_IN;

  __shared__ ushort lA[128 * 32];
  __shared__ ushort lB[128 * 32];
  const int t = threadIdx.x;
  const int lane = t & 63;
  const int w = t >> 6;
  const int wr = w >> 1, wc = w & 1;
  const int brow = rowb * 128;
  const int bcol = colb * 128;

  const int si = w * 2;
  const int srow0 = si * 16 + (lane >> 2);
  const int srow1 = (si + 1) * 16 + (lane >> 2);
  const int skk = (lane & 3) * 8;
  const ushort* gA0 = Az + (size_t)(brow + srow0) * F_IN + skk;
  const ushort* gA1 = Az + (size_t)(brow + srow1) * F_IN + skk;
  const ushort* gB0 = Bz + (size_t)(bcol + srow0) * F_IN + skk;
  const ushort* gB1 = Bz + (size_t)(bcol + srow1) * F_IN + skk;
  ushort* lA0 = lA + si * 512;
  ushort* lA1 = lA + (si + 1) * 512;
  ushort* lB0 = lB + si * 512;
  ushort* lB1 = lB + (si + 1) * 512;

  f32x4 acc[4][4] = {};
  const int frow = lane & 15;
  const int fk = (lane >> 4) * 8;

  for (int k0 = 0; k0 < F_IN; k0 += 32) {
    __builtin_amdgcn_global_load_lds((const __attribute__((address_space(1))) void*)(gA0 + k0),
                                     (__attribute__((address_space(3))) void*)lA0, 16, 0, 0);
    __builtin_amdgcn_global_load_lds((const __attribute__((address_space(1))) void*)(gA1 + k0),
                                     (__attribute__((address_space(3))) void*)lA1, 16, 0, 0);
    __builtin_amdgcn_global_load_lds((const __attribute__((address_space(1))) void*)(gB0 + k0),
                                     (__attribute__((address_space(3))) void*)lB0, 16, 0, 0);
    __builtin_amdgcn_global_load_lds((const __attribute__((address_space(1))) void*)(gB1 + k0),
                                     (__attribute__((address_space(3))) void*)lB1, 16, 0, 0);
    __syncthreads();
    bf16x8 af[4], bfr[4];
#pragma unroll
    for (int m = 0; m < 4; ++m)
      af[m] = *(const bf16x8*)(lA + (wr * 64 + m * 16 + frow) * 32 + fk);
#pragma unroll
    for (int n = 0; n < 4; ++n)
      bfr[n] = *(const bf16x8*)(lB + (wc * 64 + n * 16 + frow) * 32 + fk);
#pragma unroll
    for (int m = 0; m < 4; ++m)
#pragma unroll
      for (int n = 0; n < 4; ++n)
        acc[m][n] = __builtin_amdgcn_mfma_f32_16x16x32_bf16(af[m], bfr[n], acc[m][n], 0, 0, 0);
    __syncthreads();
  }

#pragma unroll
  for (int m = 0; m < 4; ++m) {
    const int row0 = brow + wr * 64 + m * 16 + (lane >> 4) * 4;
#pragma unroll
    for (int n = 0; n < 4; ++n) {
      const int col = bcol + wc * 64 + n * 16 + (lane & 15);
#pragma unroll
      for (int j = 0; j < 4; ++j)
        Cz[(size_t)(row0 + j) * F_IN + col] = f2bf(acc[m][n][j]);
    }
  }
}

// ---------------- GCN aggregate (bf16 h in, bf16 y out), both branches ----------------
__global__ __launch_bounds__(256) void gcn_agg2(const ushort* __restrict__ h,
                                                const int* __restrict__ rs,
                                                const int* __restrict__ esrc,
                                                const float* __restrict__ dinv,
                                                const float* __restrict__ b0,
                                                const float* __restrict__ b1,
                                                ushort* __restrict__ y) {
  const int z = blockIdx.y;
  const int node = blockIdx.x;
  const int t = threadIdx.x;
  const ushort* hz = h + (size_t)z * N_PAD * F_IN;
  const float* dv = dinv + (size_t)z * N_NODES;
  const float* bias = z ? b1 : b0;
  const float din = dv[node];
  ushort4 hv = ((const ushort4*)(hz + (size_t)node * F_IN))[t];
  const float w0 = din * din;
  float a0 = bf2f(hv.x) * w0, a1 = bf2f(hv.y) * w0, a2 = bf2f(hv.z) * w0, a3 = bf2f(hv.w) * w0;
  const int e0 = rs[(size_t)z * (N_NODES + 1) + node];
  const int e1 = rs[(size_t)z * (N_NODES + 1) + node + 1];
  const int* es = esrc + (size_t)z * N_EDGES;
  for (int e = e0; e < e1; ++e) {
    int s = es[e];
    float wgt = dv[s] * din;
    ushort4 v = ((const ushort4*)(hz + (size_t)s * F_IN))[t];
    a0 = fmaf(bf2f(v.x), wgt, a0); a1 = fmaf(bf2f(v.y), wgt, a1);
    a2 = fmaf(bf2f(v.z), wgt, a2); a3 = fmaf(bf2f(v.w), wgt, a3);
  }
  float4 bv = ((const float4*)bias)[t];
  ushort4 o;
  o.x = f2bf(leaky(a0 + bv.x)); o.y = f2bf(leaky(a1 + bv.y));
  o.z = f2bf(leaky(a2 + bv.z)); o.w = f2bf(leaky(a3 + bv.w));
  ((ushort4*)(y + ((size_t)z * N_NODES + node) * F_IN))[t] = o;
}

// ---------------- mean pool (bf16 y), both branches ----------------
__global__ __launch_bounds__(256) void pool2(const ushort* __restrict__ y,
                                             const int* __restrict__ bt0,
                                             const int* __restrict__ bt1,
                                             float* __restrict__ pool) {
  const int z = blockIdx.z;
  const int g = blockIdx.x;
  const int slice = blockIdx.y;
  const int t = threadIdx.x;
  const int* batch = z ? bt1 : bt0;
  const ushort* yz = y + (size_t)z * N_NODES * F_IN;
  int lo = lower_bound_i(batch, N_NODES, g);
  int hi = lower_bound_i(batch, N_NODES, g + 1);
  int cnt = hi - lo;
  int per = (cnt + 7) >> 3;
  int a = lo + slice * per;
  int b = min(a + per, hi);
  float s0 = 0.f, s1 = 0.f, s2 = 0.f, s3 = 0.f;
  for (int node = a; node < b; ++node) {
    ushort4 v = ((const ushort4*)(yz + (size_t)node * F_IN))[t];
    s0 += bf2f(v.x); s1 += bf2f(v.y); s2 += bf2f(v.z); s3 += bf2f(v.w);
  }
  float* pg = pool + ((size_t)z * N_GRAPHS + g) * F_IN;
  if (a < b) {
    atomicAdd(&pg[4 * t + 0], s0);
    atomicAdd(&pg[4 * t + 1], s1);
    atomicAdd(&pg[4 * t + 2], s2);
    atomicAdd(&pg[4 * t + 3], s3);
  }
}

// ---------------- FC [16,1024]@[1024,128] + bias + leaky, both branches ----------------
__global__ __launch_bounds__(128) void fc2(const float* __restrict__ pool,
                                           const int* __restrict__ bt0,
                                           const int* __restrict__ bt1,
                                           const float* __restrict__ W0,
                                           const float* __restrict__ W1,
                                           const float* __restrict__ bias0,
                                           const float* __restrict__ bias1,
                                           float* __restrict__ combined) {
  const int z = blockIdx.y;
  const int g = blockIdx.x;
  const int t = threadIdx.x;
  const int* batch = z ? bt1 : bt0;
  const float* W = z ? W1 : W0;
  const float* bias = z ? bias1 : bias0;
  __shared__ float p[F_IN];
  int lo = lower_bound_i(batch, N_NODES, g);
  int hi = lower_bound_i(batch, N_NODES, g + 1);
  float inv = 1.0f / (float)max(hi - lo, 1);
  const float* pg = pool + ((size_t)z * N_GRAPHS + g) * F_IN;
  for (int k = t; k < F_IN; k += 128) p[k] = pg[k] * inv;
  __syncthreads();
  float acc = 0.f;
  for (int k = 0; k < F_IN; ++k) acc = fmaf(p[k], W[k * D_OUT + t], acc);
  combined[g * (6 * D_OUT) + z * D_OUT + t] = leaky(acc + bias[t]);
}

// ---------------- conv1d(k=1) via MFMA ----------------
__global__ __launch_bounds__(256) void conv_mfma(const float* __restrict__ m0, const float* __restrict__ m1,
                                                 const float* __restrict__ m2, const float* __restrict__ m3,
                                                 const ushort* __restrict__ Wt,
                                                 float* __restrict__ pmax) {
  const int ch = blockIdx.x;
  const int g  = blockIdx.y;
  const int br = blockIdx.z;
  const int t  = threadIdx.x;
  const int lane = t & 63, w = t >> 6;
  const float* m = br == 0 ? m0 : br == 1 ? m1 : br == 2 ? m2 : m3;

  __shared__ __align__(16) ushort lA[128 * K_PAD];
  __shared__ __align__(16) ushort lB[D_OUT * K_PAD];
  __shared__ float smax[4 * D_OUT];

  const ushort* wsrc = Wt + (size_t)br * D_OUT * K_PAD;
  for (int i = w; i < 26; i += 4)
    __builtin_amdgcn_global_load_lds((const __attribute__((address_space(1))) void*)(wsrc + i * 512 + lane * 8),
                                     (__attribute__((address_space(3))) void*)(lB + i * 512), 16, 0, 0);

  const float4* mg4 = (const float4*)(m + ((size_t)g * SEQ_L + (size_t)ch * 128) * N_DESC);
#pragma unroll
  for (int j = 0; j < 10; ++j) {
    int fi = t + j * 256;
    int row = fi / 20, off = fi - row * 20;
    float4 v = mg4[fi];
    ushort4 o;
    o.x = f2bf(v.x); o.y = f2bf(v.y); o.z = f2bf(v.z); o.w = f2bf(v.w);
    *(ushort4*)(lA + row * K_PAD + off * 4) = o;
  }
  if (t < 128) {
    ushort4 z = {0, 0, 0, 0};
    *(ushort4*)(lA + t * K_PAD + 80) = z;
    *(ushort4*)(lA + t * K_PAD + 84) = z;
    *(ushort4*)(lA + t * K_PAD + 88) = z;
    *(ushort4*)(lA + t * K_PAD + 92) = z;
  }
  __syncthreads();

  const int frow = lane & 15, fk = (lane >> 4) * 8;
  f32x4 acc[2][8] = {};
#pragma unroll
  for (int ks = 0; ks < 3; ++ks) {
    bf16x8 af[2], bfr[8];
#pragma unroll
    for (int mm = 0; mm < 2; ++mm)
      af[mm] = *(const bf16x8*)(lA + (w * 32 + mm * 16 + frow) * K_PAD + ks * 32 + fk);
#pragma unroll
    for (int n = 0; n < 8; ++n)
      bfr[n] = *(const bf16x8*)(lB + (n * 16 + frow) * K_PAD + ks * 32 + fk);
#pragma unroll
    for (int mm = 0; mm < 2; ++mm)
#pragma unroll
      for (int n = 0; n < 8; ++n)
        acc[mm][n] = __builtin_amdgcn_mfma_f32_16x16x32_bf16(af[mm], bfr[n], acc[mm][n], 0, 0, 0);
  }

#pragma unroll
  for (int n = 0; n < 8; ++n) {
    float v = acc[0][n][0];
#pragma unroll
    for (int j = 1; j < 4; ++j) v = fmaxf(v, acc[0][n][j]);
#pragma unroll
    for (int j = 0; j < 4; ++j) v = fmaxf(v, acc[1][n][j]);
    v = fmaxf(v, __shfl_xor(v, 16, 64));
    v = fmaxf(v, __shfl_xor(v, 32, 64));
    if (lane < 16) smax[w * D_OUT + n * 16 + lane] = v;
  }
  __syncthreads();
  if (t < D_OUT) {
    float v = fmaxf(fmaxf(smax[t], smax[D_OUT + t]),
                    fmaxf(smax[2 * D_OUT + t], smax[3 * D_OUT + t]));
    pmax[(((size_t)br * N_GRAPHS + g) * N_CCH + ch) * D_OUT + t] = v;
  }
}

__global__ void conv_reduce(const float* __restrict__ pmax,
                            const float* __restrict__ b0, const float* __restrict__ b1,
                            const float* __restrict__ b2, const float* __restrict__ b3,
                            float* __restrict__ combined) {
  int i = blockIdx.x * blockDim.x + threadIdx.x;
  if (i >= 4 * N_GRAPHS * D_OUT) return;
  int br = i >> 11;
  int g = (i >> 7) & 15;
  int d = i & 127;
  const float* pm = pmax + ((size_t)(br * N_GRAPHS + g) * N_CCH) * D_OUT + d;
  float best = -3.4e38f;
#pragma unroll
  for (int ch = 0; ch < N_CCH; ++ch) best = fmaxf(best, pm[ch * D_OUT]);
  const float* bias = br == 0 ? b0 : br == 1 ? b1 : br == 2 ? b2 : b3;
  combined[g * (6 * D_OUT) + 2 * D_OUT + br * D_OUT + d] = leaky(best + bias[d]);
}

// ---------------- final linear ----------------
__global__ __launch_bounds__(256) void final_kernel(const float* __restrict__ combined,
                                                    const float* __restrict__ Wf,
                                                    const float* __restrict__ bf,
                                                    float* __restrict__ out) {
  const int g = blockIdx.x;
  const int t = threadIdx.x;
  float acc = 0.f;
  for (int k = t; k < 6 * D_OUT; k += 256) acc = fmaf(combined[g * 6 * D_OUT + k], Wf[k], acc);
  __shared__ float red[256];
  red[t] = acc;
  __syncthreads();
  for (int s = 128; s > 0; s >>= 1) {
    if (t < s) red[t] += red[t + s];
    __syncthreads();
  }
  if (t == 0) out[g] = red[0] + bf[0];
}

extern "C" void kernel_launch(void* const* d_in, const int* in_sizes, int n_in,
                              void* d_out, int out_size, void* d_ws, size_t ws_size,
                              hipStream_t stream) {
  const float* p1x  = (const float*)d_in[0];
  const int*   e1   = (const int*)d_in[1];
  const int*   bt1  = (const int*)d_in[2];
  const float* p2x  = (const float*)d_in[3];
  const int*   e2   = (const int*)d_in[4];
  const int*   bt2  = (const int*)d_in[5];
  const float* m1s  = (const float*)d_in[6];
  const float* m1f  = (const float*)d_in[7];
  const float* m2s  = (const float*)d_in[8];
  const float* m2f  = (const float*)d_in[9];
  const float* Wg1  = (const float*)d_in[10];
  const float* bg1  = (const float*)d_in[11];
  const float* Wfc1 = (const float*)d_in[12];
  const float* bfc1 = (const float*)d_in[13];
  const float* Wg2  = (const float*)d_in[14];
  const float* bg2  = (const float*)d_in[15];
  const float* Wfc2 = (const float*)d_in[16];
  const float* bfc2 = (const float*)d_in[17];
  const float* Wm1s = (const float*)d_in[18];
  const float* bm1s = (const float*)d_in[19];
  const float* Wm1f = (const float*)d_in[20];
  const float* bm1f = (const float*)d_in[21];
  const float* Wm2s = (const float*)d_in[22];
  const float* bm2s = (const float*)d_in[23];
  const float* Wm2f = (const float*)d_in[24];
  const float* bm2f = (const float*)d_in[25];
  const float* Wfin = (const float*)d_in[26];
  const float* bfin = (const float*)d_in[27];
  float* out = (float*)d_out;

  char* base = (char*)d_ws;
  size_t off = 0;
  auto alloc = [&](size_t bytes) -> void* {
    void* p = base + off;
    off = (off + bytes + 255) & ~(size_t)255;
    return p;
  };
  ushort* xbf    = (ushort*)alloc((size_t)2 * N_PAD * F_IN * 2);   // A (bf16), later aliased by ybf
  ushort* wtbf   = (ushort*)alloc((size_t)2 * F_IN * F_IN * 2);
  ushort* h      = (ushort*)alloc((size_t)2 * N_PAD * F_IN * 2);
  ushort* wtconv = (ushort*)alloc((size_t)4 * D_OUT * K_PAD * 2);
  // contiguous zero-init region: cnt, cursor, pool
  size_t zoff0 = off;
  int*    cnt    = (int*)alloc((size_t)2 * N_NODES * 4);
  int*    cursor = (int*)alloc((size_t)2 * N_NODES * 4);
  float*  pool   = (float*)alloc((size_t)2 * N_GRAPHS * F_IN * 4);
  size_t zbytes = off - zoff0;
  int*    rs     = (int*)alloc((size_t)2 * (N_NODES + 1) * 4);
  float*  dinv   = (float*)alloc((size_t)2 * N_NODES * 4);
  int*    esrc   = (int*)alloc((size_t)2 * N_EDGES * 4);
  float*  combined = (float*)alloc((size_t)N_GRAPHS * 6 * D_OUT * 4);
  float*  pmax   = (float*)alloc((size_t)4 * N_GRAPHS * N_CCH * D_OUT * 4);
  ushort* ybf    = xbf;  // alias: xbf dead after gemm2
  (void)ws_size; (void)in_sizes; (void)n_in; (void)out_size;

  hipMemsetAsync((char*)base + zoff0, 0, zbytes, stream);

  // descriptor conv branches
  conv_w_prep<<<dim3((D_OUT * K_PAD + 255) / 256, 4), 256, 0, stream>>>(Wm1s, Wm1f, Wm2s, Wm2f, wtconv);
  conv_mfma<<<dim3(N_CCH, N_GRAPHS, 4), 256, 0, stream>>>(m1s, m1f, m2s, m2f, wtconv, pmax);
  conv_reduce<<<(4 * N_GRAPHS * D_OUT + 255) / 256, 256, 0, stream>>>(pmax, bm1s, bm1f, bm2s, bm2f, combined);

  // CSR build, both branches
  count_dst2<<<dim3((N_EDGES + 255) / 256, 2), 256, 0, stream>>>(e1, e2, cnt);
  scan2<<<2, 1024, 0, stream>>>(cnt, rs, dinv);
  fill_csr2<<<dim3((N_EDGES + 255) / 256, 2), 256, 0, stream>>>(e1, e2, rs, cursor, esrc);

  // GEMM path, both branches
  const int cast_blocks = (int)(((size_t)N_PAD * F_IN / 4 + 255) / 256);
  cast_pad2<<<dim3(cast_blocks, 2), 256, 0, stream>>>(p1x, p2x, xbf);
  convT2<<<dim3(32, 32, 2), 256, 0, stream>>>(Wg1, Wg2, wtbf);
  gemm2<<<NWG_GEMM, 256, 0, stream>>>(xbf, wtbf, h);

  // aggregate + pool + fc, both branches (ybf aliases xbf)
  gcn_agg2<<<dim3(N_NODES, 2), 256, 0, stream>>>(h, rs, esrc, dinv, bg1, bg2, ybf);
  pool2<<<dim3(N_GRAPHS, 8, 2), 256, 0, stream>>>(ybf, bt1, bt2, pool);
  fc2<<<dim3(N_GRAPHS, 2), 128, 0, stream>>>(pool, bt1, bt2, Wfc1, Wfc2, bfc1, bfc2, combined);

  final_kernel<<<N_GRAPHS, 256, 0, stream>>>(combined, Wfin, bfin, out);
}

// Round 6
// 406.314 us; speedup vs baseline: 4.7694x; 1.0970x over previous
//
#include <hip/hip_runtime.h>
#include <cstdint>
#include <cstddef>

constexpr int N_NODES  = 20000;
constexpr int N_PAD    = 20096;   // 157 * 128
constexpr int N_EDGES  = 160000;
constexpr int N_GRAPHS = 16;
constexpr int SEQ_L    = 2048;
constexpr int F_IN     = 1024;
constexpr int D_OUT    = 128;
constexpr int N_DESC   = 80;
constexpr int K_PAD    = 104;     // conv: 80 padded to 96 for MFMA, 104 stride for banks
constexpr int N_CCH    = 16;      // conv: L-chunks of 128
constexpr int ELL_CAP  = 64;      // max degree capacity (Poisson(8): P(>64) ~ 1e-10)
constexpr int ROWB     = N_PAD / 128;      // 157
constexpr int NWG_GEMM = 2 * ROWB * 8;     // 2512, divisible by 8
constexpr float SLOPE  = 0.01f;

// P1 fused-kernel block ranges
constexpr int P1_CONV_END  = 1024;                    // 16 ch * 16 g * 4 br
constexpr int P1_FILL_END  = P1_CONV_END + 2 * 625;   // 160000/256 = 625 per branch
constexpr int P1_CONVT_END = P1_FILL_END + 2 * 1024;  // 32*32 per branch
constexpr int P1_CAST_END  = P1_CONVT_END + 2 * 20096;
constexpr int P1_SMEM      = 53248;                   // 2 * 128*104*2 bytes

typedef short bf16x8 __attribute__((ext_vector_type(8)));
typedef float f32x4  __attribute__((ext_vector_type(4)));

__device__ __forceinline__ float leaky(float x) { return x > 0.f ? x : SLOPE * x; }
__device__ __forceinline__ ushort f2bf(float f) {
  uint32_t u = __float_as_uint(f);
  uint32_t r = (u + 0x7FFFu + ((u >> 16) & 1u)) >> 16;
  return (ushort)r;
}
__device__ __forceinline__ float bf2f(ushort u) { return __uint_as_float(((uint32_t)u) << 16); }

__device__ __forceinline__ int lower_bound_i(const int* __restrict__ arr, int n, int val) {
  int lo = 0, hi = n;
  while (lo < hi) { int mid = (lo + hi) >> 1; if (arr[mid] < val) lo = mid + 1; else hi = mid; }
  return lo;
}

// ================= P1: conv_mfma | fill_ell | convT | cast_pad (one launch) =================
__global__ __launch_bounds__(256) void p1_fused(
    // conv branch inputs
    const float* __restrict__ m0, const float* __restrict__ m1,
    const float* __restrict__ m2, const float* __restrict__ m3,
    const float* __restrict__ Wc0, const float* __restrict__ Wc1,
    const float* __restrict__ Wc2, const float* __restrict__ Wc3,
    float* __restrict__ pmax,
    // ELL build
    const int* __restrict__ e0, const int* __restrict__ e1,
    int* __restrict__ cnt, int* __restrict__ ell,
    // GCN weight transpose
    const float* __restrict__ Wg0, const float* __restrict__ Wg1,
    ushort* __restrict__ wtbf,
    // node-feature cast
    const float* __restrict__ x0, const float* __restrict__ x1,
    ushort* __restrict__ xbf) {
  extern __shared__ char smem[];
  const int bid = blockIdx.x;
  const int t = threadIdx.x;

  if (bid < P1_CONV_END) {
    // ---- conv1d(k=1) via MFMA: [128 L-rows x 80] @ [80 x 128], max over rows ----
    ushort* lA = (ushort*)smem;                 // [128][K_PAD]
    ushort* lB = (ushort*)(smem + 26624);       // [128 col][K_PAD]
    float*  smax = (float*)smem;                // aliases lA after compute
    const int ch = bid & 15, g = (bid >> 4) & 15, br = bid >> 8;
    const float* m = br == 0 ? m0 : br == 1 ? m1 : br == 2 ? m2 : m3;
    const float* W = br == 0 ? Wc0 : br == 1 ? Wc1 : br == 2 ? Wc2 : Wc3;
    const int lane = t & 63, w = t >> 6;

    // stage B: W [80 k][128 col] f32 -> lB[col][k] bf16 (inline cast, no prep kernel)
    for (int i = t; i < N_DESC * D_OUT; i += 256) {
      int k = i >> 7, col = i & 127;
      lB[col * K_PAD + k] = f2bf(W[i]);
    }
    for (int i = t; i < 128 * 16; i += 256) {    // zero-pad k in [80,96)
      int col = i >> 4, k = 80 + (i & 15);
      lB[col * K_PAD + k] = 0;
    }
    // stage A: 128 rows x 80 f32 -> bf16
    const float4* mg4 = (const float4*)(m + ((size_t)g * SEQ_L + (size_t)ch * 128) * N_DESC);
#pragma unroll
    for (int j = 0; j < 10; ++j) {
      int fi = t + j * 256;
      int row = fi / 20, off = fi - row * 20;
      float4 v = mg4[fi];
      ushort4 o;
      o.x = f2bf(v.x); o.y = f2bf(v.y); o.z = f2bf(v.z); o.w = f2bf(v.w);
      *(ushort4*)(lA + row * K_PAD + off * 4) = o;
    }
    if (t < 128) {
      ushort4 z4 = {0, 0, 0, 0};
      *(ushort4*)(lA + t * K_PAD + 80) = z4;
      *(ushort4*)(lA + t * K_PAD + 84) = z4;
      *(ushort4*)(lA + t * K_PAD + 88) = z4;
      *(ushort4*)(lA + t * K_PAD + 92) = z4;
    }
    __syncthreads();

    const int frow = lane & 15, fk = (lane >> 4) * 8;
    f32x4 acc[2][8] = {};
#pragma unroll
    for (int ks = 0; ks < 3; ++ks) {
      bf16x8 af[2], bfr[8];
#pragma unroll
      for (int mm = 0; mm < 2; ++mm)
        af[mm] = *(const bf16x8*)(lA + (w * 32 + mm * 16 + frow) * K_PAD + ks * 32 + fk);
#pragma unroll
      for (int n = 0; n < 8; ++n)
        bfr[n] = *(const bf16x8*)(lB + (n * 16 + frow) * K_PAD + ks * 32 + fk);
#pragma unroll
      for (int mm = 0; mm < 2; ++mm)
#pragma unroll
        for (int n = 0; n < 8; ++n)
          acc[mm][n] = __builtin_amdgcn_mfma_f32_16x16x32_bf16(af[mm], bfr[n], acc[mm][n], 0, 0, 0);
    }
    __syncthreads();   // all waves done reading lA before smax (alias) writes

#pragma unroll
    for (int n = 0; n < 8; ++n) {
      float v = acc[0][n][0];
#pragma unroll
      for (int j = 1; j < 4; ++j) v = fmaxf(v, acc[0][n][j]);
#pragma unroll
      for (int j = 0; j < 4; ++j) v = fmaxf(v, acc[1][n][j]);
      v = fmaxf(v, __shfl_xor(v, 16, 64));
      v = fmaxf(v, __shfl_xor(v, 32, 64));
      if (lane < 16) smax[w * D_OUT + n * 16 + lane] = v;
    }
    __syncthreads();
    if (t < D_OUT) {
      float v = fmaxf(fmaxf(smax[t], smax[D_OUT + t]),
                      fmaxf(smax[2 * D_OUT + t], smax[3 * D_OUT + t]));
      pmax[(((size_t)br * N_GRAPHS + g) * N_CCH + ch) * D_OUT + t] = v;
    }
  } else if (bid < P1_FILL_END) {
    // ---- build ELL adjacency: slot = atomicAdd return ----
    int fb = bid - P1_CONV_END;
    int z = fb >= 625;
    int i = (fb - z * 625) * 256 + t;   // < 160000 exactly
    const int* src = z ? e1 : e0;
    const int* dst = src + N_EDGES;
    int d = dst[i];
    int pos = atomicAdd(&cnt[z * N_NODES + d], 1);
    if (pos < ELL_CAP) ell[((size_t)z * N_NODES + d) * ELL_CAP + pos] = src[i];
  } else if (bid < P1_CONVT_END) {
    // ---- W [K=1024][N=1024] f32 -> Wt [N][K] bf16 ----
    float (*tile)[33] = (float(*)[33])smem;
    int cb = bid - P1_FILL_END;
    int z = cb >= 1024;
    int cb2 = cb - z * 1024;
    const float* W = z ? Wg1 : Wg0;
    const int k0 = (cb2 & 31) * 32, n0 = (cb2 >> 5) * 32;
    const int tc = t & 31, tr = t >> 5;
#pragma unroll
    for (int q = 0; q < 4; ++q) {
      int r = tr + q * 8;
      tile[r][tc] = W[(size_t)(k0 + r) * F_IN + n0 + tc];
    }
    __syncthreads();
    ushort* Wz = wtbf + (size_t)z * F_IN * F_IN;
#pragma unroll
    for (int q = 0; q < 4; ++q) {
      int r = tr + q * 8;
      Wz[(size_t)(n0 + r) * F_IN + k0 + tc] = f2bf(tile[tc][r]);
    }
  } else {
    // ---- x [20000,1024] f32 -> [20096,1024] bf16 (pad rows zero) ----
    int cb = bid - P1_CONVT_END;
    int z = cb >= 20096;
    int cb2 = cb - z * 20096;
    const float* in = z ? x1 : x0;
    size_t i = ((size_t)cb2 * 256 + t) * 4;
    int row = (int)(i >> 10);
    ushort4 o;
    if (row < N_NODES) {
      float4 v = *(const float4*)(in + i);
      o.x = f2bf(v.x); o.y = f2bf(v.y); o.z = f2bf(v.z); o.w = f2bf(v.w);
    } else {
      o.x = o.y = o.z = o.w = 0;
    }
    *(ushort4*)(xbf + (size_t)z * N_PAD * F_IN + i) = o;
  }
}

// ================= bf16 MFMA GEMM, both branches, XCD-swizzled flat grid =================
__global__ __launch_bounds__(256) void gemm2(const ushort* __restrict__ A,
                                             const ushort* __restrict__ Bt,
                                             ushort* __restrict__ C) {
  const int bid = blockIdx.x;
  const int swz = (bid & 7) * (NWG_GEMM / 8) + (bid >> 3);
  const int br  = swz / (ROWB * 8);
  const int rem = swz - br * (ROWB * 8);
  const int rowb = rem >> 3, colb = rem & 7;

  const ushort* Az = A + (size_t)br * N_PAD * F_IN;
  const ushort* Bz = Bt + (size_t)br * F_IN * F_IN;
  ushort* Cz = C + (size_t)br * N_PAD * F_IN;

  __shared__ ushort lA[128 * 32];
  __shared__ ushort lB[128 * 32];
  const int t = threadIdx.x;
  const int lane = t & 63;
  const int w = t >> 6;
  const int wr = w >> 1, wc = w & 1;
  const int brow = rowb * 128;
  const int bcol = colb * 128;

  const int si = w * 2;
  const int srow0 = si * 16 + (lane >> 2);
  const int srow1 = (si + 1) * 16 + (lane >> 2);
  const int skk = (lane & 3) * 8;
  const ushort* gA0 = Az + (size_t)(brow + srow0) * F_IN + skk;
  const ushort* gA1 = Az + (size_t)(brow + srow1) * F_IN + skk;
  const ushort* gB0 = Bz + (size_t)(bcol + srow0) * F_IN + skk;
  const ushort* gB1 = Bz + (size_t)(bcol + srow1) * F_IN + skk;
  ushort* lA0 = lA + si * 512;
  ushort* lA1 = lA + (si + 1) * 512;
  ushort* lB0 = lB + si * 512;
  ushort* lB1 = lB + (si + 1) * 512;

  f32x4 acc[4][4] = {};
  const int frow = lane & 15;
  const int fk = (lane >> 4) * 8;

  for (int k0 = 0; k0 < F_IN; k0 += 32) {
    __builtin_amdgcn_global_load_lds((const __attribute__((address_space(1))) void*)(gA0 + k0),
                                     (__attribute__((address_space(3))) void*)lA0, 16, 0, 0);
    __builtin_amdgcn_global_load_lds((const __attribute__((address_space(1))) void*)(gA1 + k0),
                                     (__attribute__((address_space(3))) void*)lA1, 16, 0, 0);
    __builtin_amdgcn_global_load_lds((const __attribute__((address_space(1))) void*)(gB0 + k0),
                                     (__attribute__((address_space(3))) void*)lB0, 16, 0, 0);
    __builtin_amdgcn_global_load_lds((const __attribute__((address_space(1))) void*)(gB1 + k0),
                                     (__attribute__((address_space(3))) void*)lB1, 16, 0, 0);
    __syncthreads();
    bf16x8 af[4], bfr[4];
#pragma unroll
    for (int m = 0; m < 4; ++m)
      af[m] = *(const bf16x8*)(lA + (wr * 64 + m * 16 + frow) * 32 + fk);
#pragma unroll
    for (int n = 0; n < 4; ++n)
      bfr[n] = *(const bf16x8*)(lB + (wc * 64 + n * 16 + frow) * 32 + fk);
#pragma unroll
    for (int m = 0; m < 4; ++m)
#pragma unroll
      for (int n = 0; n < 4; ++n)
        acc[m][n] = __builtin_amdgcn_mfma_f32_16x16x32_bf16(af[m], bfr[n], acc[m][n], 0, 0, 0);
    __syncthreads();
  }

#pragma unroll
  for (int m = 0; m < 4; ++m) {
    const int row0 = brow + wr * 64 + m * 16 + (lane >> 4) * 4;
#pragma unroll
    for (int n = 0; n < 4; ++n) {
      const int col = bcol + wc * 64 + n * 16 + (lane & 15);
#pragma unroll
      for (int j = 0; j < 4; ++j)
        Cz[(size_t)(row0 + j) * F_IN + col] = f2bf(acc[m][n][j]);
    }
  }
}

// ================= GCN aggregate (ELL gather, bf16x8 loads, inline rsqrt) =================
__global__ __launch_bounds__(256) void gcn_agg2(const ushort* __restrict__ h,
                                                const int* __restrict__ cnt,
                                                const int* __restrict__ ell,
                                                const float* __restrict__ b0,
                                                const float* __restrict__ b1,
                                                ushort* __restrict__ y) {
  const int z = blockIdx.y;
  const int node = blockIdx.x * 2 + (threadIdx.x >> 7);
  const int lt = threadIdx.x & 127;   // 8 bf16 elems each
  const ushort* hz = h + (size_t)z * N_PAD * F_IN;
  const int* cz = cnt + (size_t)z * N_NODES;
  const int deg = cz[node];
  const float din = rsqrtf((float)(deg + 1));
  bf16x8 hv = ((const bf16x8*)(hz + (size_t)node * F_IN))[lt];
  const float w0 = din * din;
  float acc[8];
#pragma unroll
  for (int j = 0; j < 8; ++j) acc[j] = bf2f((ushort)hv[j]) * w0;
  const int* el = ell + ((size_t)z * N_NODES + node) * ELL_CAP;
  const int ne = min(deg, ELL_CAP);
  for (int e = 0; e < ne; ++e) {
    int s = el[e];
    float wgt = rsqrtf((float)(cz[s] + 1)) * din;
    bf16x8 v = ((const bf16x8*)(hz + (size_t)s * F_IN))[lt];
#pragma unroll
    for (int j = 0; j < 8; ++j) acc[j] = fmaf(bf2f((ushort)v[j]), wgt, acc[j]);
  }
  const float* bias = z ? b1 : b0;
  float bv[8];
  *(float4*)(bv)     = ((const float4*)bias)[lt * 2];
  *(float4*)(bv + 4) = ((const float4*)bias)[lt * 2 + 1];
  bf16x8 ov;
#pragma unroll
  for (int j = 0; j < 8; ++j) ov[j] = (short)f2bf(leaky(acc[j] + bv[j]));
  ((bf16x8*)(y + ((size_t)z * N_NODES + node) * F_IN))[lt] = ov;
}

// ================= mean pool (bf16 y), both branches =================
__global__ __launch_bounds__(256) void pool2(const ushort* __restrict__ y,
                                             const int* __restrict__ bt0,
                                             const int* __restrict__ bt1,
                                             float* __restrict__ pool) {
  const int z = blockIdx.z;
  const int g = blockIdx.x;
  const int slice = blockIdx.y;
  const int t = threadIdx.x;
  const int* batch = z ? bt1 : bt0;
  const ushort* yz = y + (size_t)z * N_NODES * F_IN;
  int lo = lower_bound_i(batch, N_NODES, g);
  int hi = lower_bound_i(batch, N_NODES, g + 1);
  int cntn = hi - lo;
  int per = (cntn + 7) >> 3;
  int a = lo + slice * per;
  int b = min(a + per, hi);
  float s0 = 0.f, s1 = 0.f, s2 = 0.f, s3 = 0.f;
  for (int node = a; node < b; ++node) {
    ushort4 v = ((const ushort4*)(yz + (size_t)node * F_IN))[t];
    s0 += bf2f(v.x); s1 += bf2f(v.y); s2 += bf2f(v.z); s3 += bf2f(v.w);
  }
  float* pg = pool + ((size_t)z * N_GRAPHS + g) * F_IN;
  if (a < b) {
    atomicAdd(&pg[4 * t + 0], s0);
    atomicAdd(&pg[4 * t + 1], s1);
    atomicAdd(&pg[4 * t + 2], s2);
    atomicAdd(&pg[4 * t + 3], s3);
  }
}

// ================= T1: conv_reduce | fc, fused =================
__global__ __launch_bounds__(256) void tail1(const float* __restrict__ pmax,
                                             const float* __restrict__ cb0, const float* __restrict__ cb1,
                                             const float* __restrict__ cb2, const float* __restrict__ cb3,
                                             const float* __restrict__ pool,
                                             const int* __restrict__ bt0, const int* __restrict__ bt1,
                                             const float* __restrict__ W0, const float* __restrict__ W1,
                                             const float* __restrict__ fb0, const float* __restrict__ fb1,
                                             float* __restrict__ combined) {
  __shared__ float p[2][F_IN];
  const int bid = blockIdx.x;
  const int t = threadIdx.x;
  if (bid < 32) {
    // conv max-reduce over 16 chunks + bias + leaky
    int i = bid * 256 + t;          // < 8192 = 4*16*128
    int br = i >> 11;
    int g = (i >> 7) & 15;
    int d = i & 127;
    const float* pm = pmax + ((size_t)(br * N_GRAPHS + g) * N_CCH) * D_OUT + d;
    float best = -3.4e38f;
#pragma unroll
    for (int ch = 0; ch < N_CCH; ++ch) best = fmaxf(best, pm[ch * D_OUT]);
    const float* bias = br == 0 ? cb0 : br == 1 ? cb1 : br == 2 ? cb2 : cb3;
    combined[g * (6 * D_OUT) + 2 * D_OUT + br * D_OUT + d] = leaky(best + bias[d]);
  } else {
    // FC [16,1024]@[1024,128], 2 (z,g) pairs per block
    int idx = (bid - 32) * 2 + (t >> 7);
    int z = idx >> 4, g = idx & 15;
    int tt = t & 127, sub = t >> 7;
    const int* batch = z ? bt1 : bt0;
    const float* W = z ? W1 : W0;
    const float* bias = z ? fb1 : fb0;
    int lo = lower_bound_i(batch, N_NODES, g);
    int hi = lower_bound_i(batch, N_NODES, g + 1);
    float inv = 1.0f / (float)max(hi - lo, 1);
    const float* pg = pool + ((size_t)z * N_GRAPHS + g) * F_IN;
    for (int k = tt; k < F_IN; k += 128) p[sub][k] = pg[k] * inv;
    __syncthreads();
    float acc = 0.f;
    for (int k = 0; k < F_IN; ++k) acc = fmaf(p[sub][k], W[k * D_OUT + tt], acc);
    combined[g * (6 * D_OUT) + z * D_OUT + tt] = leaky(acc + bias[tt]);
  }
}

// ================= final linear =================
__global__ __launch_bounds__(256) void final_kernel(const float* __restrict__ combined,
                                                    const float* __restrict__ Wf,
                                                    const float* __restrict__ bf,
                                                    float* __restrict__ out) {
  const int g = blockIdx.x;
  const int t = threadIdx.x;
  float acc = 0.f;
  for (int k = t; k < 6 * D_OUT; k += 256) acc = fmaf(combined[g * 6 * D_OUT + k], Wf[k], acc);
  __shared__ float red[256];
  red[t] = acc;
  __syncthreads();
  for (int s = 128; s > 0; s >>= 1) {
    if (t < s) red[t] += red[t + s];
    __syncthreads();
  }
  if (t == 0) out[g] = red[0] + bf[0];
}

extern "C" void kernel_launch(void* const* d_in, const int* in_sizes, int n_in,
                              void* d_out, int out_size, void* d_ws, size_t ws_size,
                              hipStream_t stream) {
  const float* p1x  = (const float*)d_in[0];
  const int*   e1   = (const int*)d_in[1];
  const int*   bt1  = (const int*)d_in[2];
  const float* p2x  = (const float*)d_in[3];
  const int*   e2   = (const int*)d_in[4];
  const int*   bt2  = (const int*)d_in[5];
  const float* m1s  = (const float*)d_in[6];
  const float* m1f  = (const float*)d_in[7];
  const float* m2s  = (const float*)d_in[8];
  const float* m2f  = (const float*)d_in[9];
  const float* Wg1  = (const float*)d_in[10];
  const float* bg1  = (const float*)d_in[11];
  const float* Wfc1 = (const float*)d_in[12];
  const float* bfc1 = (const float*)d_in[13];
  const float* Wg2  = (const float*)d_in[14];
  const float* bg2  = (const float*)d_in[15];
  const float* Wfc2 = (const float*)d_in[16];
  const float* bfc2 = (const float*)d_in[17];
  const float* Wm1s = (const float*)d_in[18];
  const float* bm1s = (const float*)d_in[19];
  const float* Wm1f = (const float*)d_in[20];
  const float* bm1f = (const float*)d_in[21];
  const float* Wm2s = (const float*)d_in[22];
  const float* bm2s = (const float*)d_in[23];
  const float* Wm2f = (const float*)d_in[24];
  const float* bm2f = (const float*)d_in[25];
  const float* Wfin = (const float*)d_in[26];
  const float* bfin = (const float*)d_in[27];
  float* out = (float*)d_out;

  char* base = (char*)d_ws;
  size_t off = 0;
  auto alloc = [&](size_t bytes) -> void* {
    void* p = base + off;
    off = (off + bytes + 255) & ~(size_t)255;
    return p;
  };
  ushort* xbf    = (ushort*)alloc((size_t)2 * N_PAD * F_IN * 2);   // later aliased by ybf
  ushort* wtbf   = (ushort*)alloc((size_t)2 * F_IN * F_IN * 2);
  ushort* h      = (ushort*)alloc((size_t)2 * N_PAD * F_IN * 2);
  // contiguous zero-init region: cnt, pool
  size_t zoff0 = off;
  int*    cnt    = (int*)alloc((size_t)2 * N_NODES * 4);
  float*  pool   = (float*)alloc((size_t)2 * N_GRAPHS * F_IN * 4);
  size_t zbytes = off - zoff0;
  int*    ell    = (int*)alloc((size_t)2 * N_NODES * ELL_CAP * 4);
  float*  combined = (float*)alloc((size_t)N_GRAPHS * 6 * D_OUT * 4);
  float*  pmax   = (float*)alloc((size_t)4 * N_GRAPHS * N_CCH * D_OUT * 4);
  ushort* ybf    = xbf;  // alias: xbf dead after gemm2
  (void)ws_size; (void)in_sizes; (void)n_in; (void)out_size;

  hipMemsetAsync((char*)base + zoff0, 0, zbytes, stream);

  // P1: conv_mfma | fill_ell | convT | cast  (one fused launch)
  p1_fused<<<P1_CAST_END, 256, P1_SMEM, stream>>>(
      m1s, m1f, m2s, m2f, Wm1s, Wm1f, Wm2s, Wm2f, pmax,
      e1, e2, cnt, ell,
      Wg1, Wg2, wtbf,
      p1x, p2x, xbf);

  gemm2<<<NWG_GEMM, 256, 0, stream>>>(xbf, wtbf, h);

  gcn_agg2<<<dim3(N_NODES / 2, 2), 256, 0, stream>>>(h, cnt, ell, bg1, bg2, ybf);

  pool2<<<dim3(N_GRAPHS, 8, 2), 256, 0, stream>>>(ybf, bt1, bt2, pool);

  tail1<<<48, 256, 0, stream>>>(pmax, bm1s, bm1f, bm2s, bm2f,
                                pool, bt1, bt2, Wfc1, Wfc2, bfc1, bfc2, combined);

  final_kernel<<<N_GRAPHS, 256, 0, stream>>>(combined, Wfin, bfin, out);
}

// Round 7
// 404.324 us; speedup vs baseline: 4.7928x; 1.0049x over previous
//
#include <hip/hip_runtime.h>
#include <cstdint>
#include <cstddef>

constexpr int N_NODES  = 20000;
constexpr int N_PAD    = 20096;   // 157 * 128
constexpr int N_EDGES  = 160000;
constexpr int N_GRAPHS = 16;
constexpr int SEQ_L    = 2048;
constexpr int F_IN     = 1024;
constexpr int D_OUT    = 128;
constexpr int N_DESC   = 80;
constexpr int K_PAD    = 104;     // conv: 80 padded to 96 for MFMA, 104 stride for banks
constexpr int N_CCH    = 16;      // conv: L-chunks of 128
constexpr int ELL_CAP  = 64;      // max degree capacity (Poisson(8): P(>64) ~ 1e-10)
constexpr int ROWB     = N_PAD / 128;      // 157
constexpr int NWG_GEMM = 2 * ROWB * 8;     // 2512, divisible by 8
constexpr float SLOPE  = 0.01f;

// P1 fused-kernel block ranges
constexpr int P1_CONV_END  = 1024;                    // 16 ch * 16 g * 4 br
constexpr int P1_FILL_END  = P1_CONV_END + 2 * 625;   // 160000/256 = 625 per branch
constexpr int P1_CONVT_END = P1_FILL_END + 2 * 1024;  // 32*32 per branch
constexpr int P1_CAST_END  = P1_CONVT_END + 2 * 20096;
constexpr int P1_SMEM      = 53248;                   // 2 * 128*104*2 bytes

typedef short bf16x8 __attribute__((ext_vector_type(8)));
typedef float f32x4  __attribute__((ext_vector_type(4)));

__device__ __forceinline__ float leaky(float x) { return x > 0.f ? x : SLOPE * x; }
__device__ __forceinline__ ushort f2bf(float f) {
  uint32_t u = __float_as_uint(f);
  uint32_t r = (u + 0x7FFFu + ((u >> 16) & 1u)) >> 16;
  return (ushort)r;
}
__device__ __forceinline__ float bf2f(ushort u) { return __uint_as_float(((uint32_t)u) << 16); }

__device__ __forceinline__ int lower_bound_i(const int* __restrict__ arr, int n, int val) {
  int lo = 0, hi = n;
  while (lo < hi) { int mid = (lo + hi) >> 1; if (arr[mid] < val) lo = mid + 1; else hi = mid; }
  return lo;
}

// ================= P1: conv_mfma | fill_ell | convT | cast_pad (one launch) =================
__global__ __launch_bounds__(256) void p1_fused(
    const float* __restrict__ m0, const float* __restrict__ m1,
    const float* __restrict__ m2, const float* __restrict__ m3,
    const float* __restrict__ Wc0, const float* __restrict__ Wc1,
    const float* __restrict__ Wc2, const float* __restrict__ Wc3,
    float* __restrict__ pmax,
    const int* __restrict__ e0, const int* __restrict__ e1,
    int* __restrict__ cnt, int* __restrict__ ell,
    const float* __restrict__ Wg0, const float* __restrict__ Wg1,
    ushort* __restrict__ wtbf,
    const float* __restrict__ x0, const float* __restrict__ x1,
    ushort* __restrict__ xbf) {
  extern __shared__ char smem[];
  const int bid = blockIdx.x;
  const int t = threadIdx.x;

  if (bid < P1_CONV_END) {
    // ---- conv1d(k=1) via MFMA: [128 L-rows x 80] @ [80 x 128], max over rows ----
    ushort* lA = (ushort*)smem;                 // [128][K_PAD]
    ushort* lB = (ushort*)(smem + 26624);       // [128 col][K_PAD]
    float*  smax = (float*)smem;                // aliases lA after compute
    const int ch = bid & 15, g = (bid >> 4) & 15, br = bid >> 8;
    const float* m = br == 0 ? m0 : br == 1 ? m1 : br == 2 ? m2 : m3;
    const float* W = br == 0 ? Wc0 : br == 1 ? Wc1 : br == 2 ? Wc2 : Wc3;
    const int lane = t & 63, w = t >> 6;

    for (int i = t; i < N_DESC * D_OUT; i += 256) {
      int k = i >> 7, col = i & 127;
      lB[col * K_PAD + k] = f2bf(W[i]);
    }
    for (int i = t; i < 128 * 16; i += 256) {
      int col = i >> 4, k = 80 + (i & 15);
      lB[col * K_PAD + k] = 0;
    }
    const float4* mg4 = (const float4*)(m + ((size_t)g * SEQ_L + (size_t)ch * 128) * N_DESC);
#pragma unroll
    for (int j = 0; j < 10; ++j) {
      int fi = t + j * 256;
      int row = fi / 20, off = fi - row * 20;
      float4 v = mg4[fi];
      ushort4 o;
      o.x = f2bf(v.x); o.y = f2bf(v.y); o.z = f2bf(v.z); o.w = f2bf(v.w);
      *(ushort4*)(lA + row * K_PAD + off * 4) = o;
    }
    if (t < 128) {
      ushort4 z4 = {0, 0, 0, 0};
      *(ushort4*)(lA + t * K_PAD + 80) = z4;
      *(ushort4*)(lA + t * K_PAD + 84) = z4;
      *(ushort4*)(lA + t * K_PAD + 88) = z4;
      *(ushort4*)(lA + t * K_PAD + 92) = z4;
    }
    __syncthreads();

    const int frow = lane & 15, fk = (lane >> 4) * 8;
    f32x4 acc[2][8] = {};
#pragma unroll
    for (int ks = 0; ks < 3; ++ks) {
      bf16x8 af[2], bfr[8];
#pragma unroll
      for (int mm = 0; mm < 2; ++mm)
        af[mm] = *(const bf16x8*)(lA + (w * 32 + mm * 16 + frow) * K_PAD + ks * 32 + fk);
#pragma unroll
      for (int n = 0; n < 8; ++n)
        bfr[n] = *(const bf16x8*)(lB + (n * 16 + frow) * K_PAD + ks * 32 + fk);
#pragma unroll
      for (int mm = 0; mm < 2; ++mm)
#pragma unroll
        for (int n = 0; n < 8; ++n)
          acc[mm][n] = __builtin_amdgcn_mfma_f32_16x16x32_bf16(af[mm], bfr[n], acc[mm][n], 0, 0, 0);
    }
    __syncthreads();

#pragma unroll
    for (int n = 0; n < 8; ++n) {
      float v = acc[0][n][0];
#pragma unroll
      for (int j = 1; j < 4; ++j) v = fmaxf(v, acc[0][n][j]);
#pragma unroll
      for (int j = 0; j < 4; ++j) v = fmaxf(v, acc[1][n][j]);
      v = fmaxf(v, __shfl_xor(v, 16, 64));
      v = fmaxf(v, __shfl_xor(v, 32, 64));
      if (lane < 16) smax[w * D_OUT + n * 16 + lane] = v;
    }
    __syncthreads();
    if (t < D_OUT) {
      float v = fmaxf(fmaxf(smax[t], smax[D_OUT + t]),
                      fmaxf(smax[2 * D_OUT + t], smax[3 * D_OUT + t]));
      pmax[(((size_t)br * N_GRAPHS + g) * N_CCH + ch) * D_OUT + t] = v;
    }
  } else if (bid < P1_FILL_END) {
    // ---- build ELL adjacency ----
    int fb = bid - P1_CONV_END;
    int z = fb >= 625;
    int i = (fb - z * 625) * 256 + t;
    const int* src = z ? e1 : e0;
    const int* dst = src + N_EDGES;
    int d = dst[i];
    int pos = atomicAdd(&cnt[z * N_NODES + d], 1);
    if (pos < ELL_CAP) ell[((size_t)z * N_NODES + d) * ELL_CAP + pos] = src[i];
  } else if (bid < P1_CONVT_END) {
    // ---- W [K=1024][N=1024] f32 -> Wt [N][K] bf16 ----
    float (*tile)[33] = (float(*)[33])smem;
    int cb = bid - P1_FILL_END;
    int z = cb >= 1024;
    int cb2 = cb - z * 1024;
    const float* W = z ? Wg1 : Wg0;
    const int k0 = (cb2 & 31) * 32, n0 = (cb2 >> 5) * 32;
    const int tc = t & 31, tr = t >> 5;
#pragma unroll
    for (int q = 0; q < 4; ++q) {
      int r = tr + q * 8;
      tile[r][tc] = W[(size_t)(k0 + r) * F_IN + n0 + tc];
    }
    __syncthreads();
    ushort* Wz = wtbf + (size_t)z * F_IN * F_IN;
#pragma unroll
    for (int q = 0; q < 4; ++q) {
      int r = tr + q * 8;
      Wz[(size_t)(n0 + r) * F_IN + k0 + tc] = f2bf(tile[tc][r]);
    }
  } else {
    // ---- x cast/pad ----
    int cb = bid - P1_CONVT_END;
    int z = cb >= 20096;
    int cb2 = cb - z * 20096;
    const float* in = z ? x1 : x0;
    size_t i = ((size_t)cb2 * 256 + t) * 4;
    int row = (int)(i >> 10);
    ushort4 o;
    if (row < N_NODES) {
      float4 v = *(const float4*)(in + i);
      o.x = f2bf(v.x); o.y = f2bf(v.y); o.z = f2bf(v.z); o.w = f2bf(v.w);
    } else {
      o.x = o.y = o.z = o.w = 0;
    }
    *(ushort4*)(xbf + (size_t)z * N_PAD * F_IN + i) = o;
  }
}

// ========== bf16 MFMA GEMM, BK=64 (2 sub-tiles/barrier), dinv-scaled epilogue ==========
// stores hs[row] = rsqrt(cnt[row]+1) * (x @ W)[row]  (bf16)
__global__ __launch_bounds__(256) void gemm2(const ushort* __restrict__ A,
                                             const ushort* __restrict__ Bt,
                                             const int* __restrict__ cnt,
                                             ushort* __restrict__ C) {
  const int bid = blockIdx.x;
  const int swz = (bid & 7) * (NWG_GEMM / 8) + (bid >> 3);
  const int br  = swz / (ROWB * 8);
  const int rem = swz - br * (ROWB * 8);
  const int rowb = rem >> 3, colb = rem & 7;

  const ushort* Az = A + (size_t)br * N_PAD * F_IN;
  const ushort* Bz = Bt + (size_t)br * F_IN * F_IN;
  ushort* Cz = C + (size_t)br * N_PAD * F_IN;
  const int* cz = cnt + br * N_NODES;

  __shared__ ushort lA[2][128 * 32];
  __shared__ ushort lB[2][128 * 32];
  const int t = threadIdx.x;
  const int lane = t & 63;
  const int w = t >> 6;
  const int wr = w >> 1, wc = w & 1;
  const int brow = rowb * 128;
  const int bcol = colb * 128;

  const int si = w * 2;
  const int srow0 = si * 16 + (lane >> 2);
  const int srow1 = (si + 1) * 16 + (lane >> 2);
  const int skk = (lane & 3) * 8;
  const ushort* gA0 = Az + (size_t)(brow + srow0) * F_IN + skk;
  const ushort* gA1 = Az + (size_t)(brow + srow1) * F_IN + skk;
  const ushort* gB0 = Bz + (size_t)(bcol + srow0) * F_IN + skk;
  const ushort* gB1 = Bz + (size_t)(bcol + srow1) * F_IN + skk;

  f32x4 acc[4][4] = {};
  const int frow = lane & 15;
  const int fk = (lane >> 4) * 8;

  for (int k0 = 0; k0 < F_IN; k0 += 64) {
#pragma unroll
    for (int ks = 0; ks < 2; ++ks) {
      const int ko = k0 + ks * 32;
      __builtin_amdgcn_global_load_lds((const __attribute__((address_space(1))) void*)(gA0 + ko),
                                       (__attribute__((address_space(3))) void*)(lA[ks] + si * 512), 16, 0, 0);
      __builtin_amdgcn_global_load_lds((const __attribute__((address_space(1))) void*)(gA1 + ko),
                                       (__attribute__((address_space(3))) void*)(lA[ks] + (si + 1) * 512), 16, 0, 0);
      __builtin_amdgcn_global_load_lds((const __attribute__((address_space(1))) void*)(gB0 + ko),
                                       (__attribute__((address_space(3))) void*)(lB[ks] + si * 512), 16, 0, 0);
      __builtin_amdgcn_global_load_lds((const __attribute__((address_space(1))) void*)(gB1 + ko),
                                       (__attribute__((address_space(3))) void*)(lB[ks] + (si + 1) * 512), 16, 0, 0);
    }
    __syncthreads();
#pragma unroll
    for (int ks = 0; ks < 2; ++ks) {
      bf16x8 af[4], bfr[4];
#pragma unroll
      for (int m = 0; m < 4; ++m)
        af[m] = *(const bf16x8*)(lA[ks] + (wr * 64 + m * 16 + frow) * 32 + fk);
#pragma unroll
      for (int n = 0; n < 4; ++n)
        bfr[n] = *(const bf16x8*)(lB[ks] + (wc * 64 + n * 16 + frow) * 32 + fk);
#pragma unroll
      for (int m = 0; m < 4; ++m)
#pragma unroll
        for (int n = 0; n < 4; ++n)
          acc[m][n] = __builtin_amdgcn_mfma_f32_16x16x32_bf16(af[m], bfr[n], acc[m][n], 0, 0, 0);
    }
    __syncthreads();
  }

#pragma unroll
  for (int m = 0; m < 4; ++m) {
    const int row0 = brow + wr * 64 + m * 16 + (lane >> 4) * 4;
#pragma unroll
    for (int j = 0; j < 4; ++j) {
      const int row = row0 + j;
      const float dv = (row < N_NODES) ? rsqrtf((float)(cz[row] + 1)) : 0.f;
#pragma unroll
      for (int n = 0; n < 4; ++n) {
        const int col = bcol + wc * 64 + n * 16 + (lane & 15);
        Cz[(size_t)row * F_IN + col] = f2bf(acc[m][n][j] * dv);
      }
    }
  }
}

// ===== GCN aggregate: y = leaky(din * (hs[node] + sum_nb hs[s]) + b)  (pure-add gather) =====
__global__ __launch_bounds__(256) void gcn_agg2(const ushort* __restrict__ hs,
                                                const int* __restrict__ cnt,
                                                const int* __restrict__ ell,
                                                const float* __restrict__ b0,
                                                const float* __restrict__ b1,
                                                ushort* __restrict__ y) {
  const int z = blockIdx.y;
  const int node = blockIdx.x * 2 + (threadIdx.x >> 7);
  const int lt = threadIdx.x & 127;   // 8 bf16 elems each
  const ushort* hz = hs + (size_t)z * N_PAD * F_IN;
  const int deg = cnt[z * N_NODES + node];
  const float din = rsqrtf((float)(deg + 1));
  bf16x8 hv = ((const bf16x8*)(hz + (size_t)node * F_IN))[lt];
  float acc[8];
#pragma unroll
  for (int j = 0; j < 8; ++j) acc[j] = bf2f((ushort)hv[j]);
  const int* el = ell + ((size_t)z * N_NODES + node) * ELL_CAP;
  const int ne = min(deg, ELL_CAP);
  int e = 0;
  for (; e + 2 <= ne; e += 2) {
    int s0 = el[e], s1 = el[e + 1];
    bf16x8 v0 = ((const bf16x8*)(hz + (size_t)s0 * F_IN))[lt];
    bf16x8 v1 = ((const bf16x8*)(hz + (size_t)s1 * F_IN))[lt];
#pragma unroll
    for (int j = 0; j < 8; ++j) acc[j] += bf2f((ushort)v0[j]) + bf2f((ushort)v1[j]);
  }
  if (e < ne) {
    int s0 = el[e];
    bf16x8 v0 = ((const bf16x8*)(hz + (size_t)s0 * F_IN))[lt];
#pragma unroll
    for (int j = 0; j < 8; ++j) acc[j] += bf2f((ushort)v0[j]);
  }
  const float* bias = z ? b1 : b0;
  float bv[8];
  *(float4*)(bv)     = ((const float4*)bias)[lt * 2];
  *(float4*)(bv + 4) = ((const float4*)bias)[lt * 2 + 1];
  bf16x8 ov;
#pragma unroll
  for (int j = 0; j < 8; ++j) ov[j] = (short)f2bf(leaky(din * acc[j] + bv[j]));
  ((bf16x8*)(y + ((size_t)z * N_NODES + node) * F_IN))[lt] = ov;
}

// ================= mean pool (bf16 y), both branches =================
__global__ __launch_bounds__(256) void pool2(const ushort* __restrict__ y,
                                             const int* __restrict__ bt0,
                                             const int* __restrict__ bt1,
                                             float* __restrict__ pool) {
  const int z = blockIdx.z;
  const int g = blockIdx.x;
  const int slice = blockIdx.y;
  const int t = threadIdx.x;
  const int* batch = z ? bt1 : bt0;
  const ushort* yz = y + (size_t)z * N_NODES * F_IN;
  int lo = lower_bound_i(batch, N_NODES, g);
  int hi = lower_bound_i(batch, N_NODES, g + 1);
  int cntn = hi - lo;
  int per = (cntn + 7) >> 3;
  int a = lo + slice * per;
  int b = min(a + per, hi);
  float s0 = 0.f, s1 = 0.f, s2 = 0.f, s3 = 0.f;
  for (int node = a; node < b; ++node) {
    ushort4 v = ((const ushort4*)(yz + (size_t)node * F_IN))[t];
    s0 += bf2f(v.x); s1 += bf2f(v.y); s2 += bf2f(v.z); s3 += bf2f(v.w);
  }
  float* pg = pool + ((size_t)z * N_GRAPHS + g) * F_IN;
  if (a < b) {
    atomicAdd(&pg[4 * t + 0], s0);
    atomicAdd(&pg[4 * t + 1], s1);
    atomicAdd(&pg[4 * t + 2], s2);
    atomicAdd(&pg[4 * t + 3], s3);
  }
}

// ================= T1: conv_reduce | fc, fused =================
__global__ __launch_bounds__(256) void tail1(const float* __restrict__ pmax,
                                             const float* __restrict__ cb0, const float* __restrict__ cb1,
                                             const float* __restrict__ cb2, const float* __restrict__ cb3,
                                             const float* __restrict__ pool,
                                             const int* __restrict__ bt0, const int* __restrict__ bt1,
                                             const float* __restrict__ W0, const float* __restrict__ W1,
                                             const float* __restrict__ fb0, const float* __restrict__ fb1,
                                             float* __restrict__ combined) {
  __shared__ float p[2][F_IN];
  const int bid = blockIdx.x;
  const int t = threadIdx.x;
  if (bid < 32) {
    int i = bid * 256 + t;
    int br = i >> 11;
    int g = (i >> 7) & 15;
    int d = i & 127;
    const float* pm = pmax + ((size_t)(br * N_GRAPHS + g) * N_CCH) * D_OUT + d;
    float best = -3.4e38f;
#pragma unroll
    for (int ch = 0; ch < N_CCH; ++ch) best = fmaxf(best, pm[ch * D_OUT]);
    const float* bias = br == 0 ? cb0 : br == 1 ? cb1 : br == 2 ? cb2 : cb3;
    combined[g * (6 * D_OUT) + 2 * D_OUT + br * D_OUT + d] = leaky(best + bias[d]);
  } else {
    int idx = (bid - 32) * 2 + (t >> 7);
    int z = idx >> 4, g = idx & 15;
    int tt = t & 127, sub = t >> 7;
    const int* batch = z ? bt1 : bt0;
    const float* W = z ? W1 : W0;
    const float* bias = z ? fb1 : fb0;
    int lo = lower_bound_i(batch, N_NODES, g);
    int hi = lower_bound_i(batch, N_NODES, g + 1);
    float inv = 1.0f / (float)max(hi - lo, 1);
    const float* pg = pool + ((size_t)z * N_GRAPHS + g) * F_IN;
    for (int k = tt; k < F_IN; k += 128) p[sub][k] = pg[k] * inv;
    __syncthreads();
    float acc = 0.f;
    for (int k = 0; k < F_IN; ++k) acc = fmaf(p[sub][k], W[k * D_OUT + tt], acc);
    combined[g * (6 * D_OUT) + z * D_OUT + tt] = leaky(acc + bias[tt]);
  }
}

// ================= final linear =================
__global__ __launch_bounds__(256) void final_kernel(const float* __restrict__ combined,
                                                    const float* __restrict__ Wf,
                                                    const float* __restrict__ bf,
                                                    float* __restrict__ out) {
  const int g = blockIdx.x;
  const int t = threadIdx.x;
  float acc = 0.f;
  for (int k = t; k < 6 * D_OUT; k += 256) acc = fmaf(combined[g * 6 * D_OUT + k], Wf[k], acc);
  __shared__ float red[256];
  red[t] = acc;
  __syncthreads();
  for (int s = 128; s > 0; s >>= 1) {
    if (t < s) red[t] += red[t + s];
    __syncthreads();
  }
  if (t == 0) out[g] = red[0] + bf[0];
}

extern "C" void kernel_launch(void* const* d_in, const int* in_sizes, int n_in,
                              void* d_out, int out_size, void* d_ws, size_t ws_size,
                              hipStream_t stream) {
  const float* p1x  = (const float*)d_in[0];
  const int*   e1   = (const int*)d_in[1];
  const int*   bt1  = (const int*)d_in[2];
  const float* p2x  = (const float*)d_in[3];
  const int*   e2   = (const int*)d_in[4];
  const int*   bt2  = (const int*)d_in[5];
  const float* m1s  = (const float*)d_in[6];
  const float* m1f  = (const float*)d_in[7];
  const float* m2s  = (const float*)d_in[8];
  const float* m2f  = (const float*)d_in[9];
  const float* Wg1  = (const float*)d_in[10];
  const float* bg1  = (const float*)d_in[11];
  const float* Wfc1 = (const float*)d_in[12];
  const float* bfc1 = (const float*)d_in[13];
  const float* Wg2  = (const float*)d_in[14];
  const float* bg2  = (const float*)d_in[15];
  const float* Wfc2 = (const float*)d_in[16];
  const float* bfc2 = (const float*)d_in[17];
  const float* Wm1s = (const float*)d_in[18];
  const float* bm1s = (const float*)d_in[19];
  const float* Wm1f = (const float*)d_in[20];
  const float* bm1f = (const float*)d_in[21];
  const float* Wm2s = (const float*)d_in[22];
  const float* bm2s = (const float*)d_in[23];
  const float* Wm2f = (const float*)d_in[24];
  const float* bm2f = (const float*)d_in[25];
  const float* Wfin = (const float*)d_in[26];
  const float* bfin = (const float*)d_in[27];
  float* out = (float*)d_out;

  char* base = (char*)d_ws;
  size_t off = 0;
  auto alloc = [&](size_t bytes) -> void* {
    void* p = base + off;
    off = (off + bytes + 255) & ~(size_t)255;
    return p;
  };
  ushort* xbf    = (ushort*)alloc((size_t)2 * N_PAD * F_IN * 2);   // later aliased by ybf
  ushort* wtbf   = (ushort*)alloc((size_t)2 * F_IN * F_IN * 2);
  ushort* h      = (ushort*)alloc((size_t)2 * N_PAD * F_IN * 2);
  // contiguous zero-init region: cnt, pool
  size_t zoff0 = off;
  int*    cnt    = (int*)alloc((size_t)2 * N_NODES * 4);
  float*  pool   = (float*)alloc((size_t)2 * N_GRAPHS * F_IN * 4);
  size_t zbytes = off - zoff0;
  int*    ell    = (int*)alloc((size_t)2 * N_NODES * ELL_CAP * 4);
  float*  combined = (float*)alloc((size_t)N_GRAPHS * 6 * D_OUT * 4);
  float*  pmax   = (float*)alloc((size_t)4 * N_GRAPHS * N_CCH * D_OUT * 4);
  ushort* ybf    = xbf;  // alias: xbf dead after gemm2
  (void)ws_size; (void)in_sizes; (void)n_in; (void)out_size;

  hipMemsetAsync((char*)base + zoff0, 0, zbytes, stream);

  // P1: conv_mfma | fill_ell | convT | cast  (one fused launch)
  p1_fused<<<P1_CAST_END, 256, P1_SMEM, stream>>>(
      m1s, m1f, m2s, m2f, Wm1s, Wm1f, Wm2s, Wm2f, pmax,
      e1, e2, cnt, ell,
      Wg1, Wg2, wtbf,
      p1x, p2x, xbf);

  gemm2<<<NWG_GEMM, 256, 0, stream>>>(xbf, wtbf, cnt, h);

  gcn_agg2<<<dim3(N_NODES / 2, 2), 256, 0, stream>>>(h, cnt, ell, bg1, bg2, ybf);

  pool2<<<dim3(N_GRAPHS, 8, 2), 256, 0, stream>>>(ybf, bt1, bt2, pool);

  tail1<<<48, 256, 0, stream>>>(pmax, bm1s, bm1f, bm2s, bm2f,
                                pool, bt1, bt2, Wfc1, Wfc2, bfc1, bfc2, combined);

  final_kernel<<<N_GRAPHS, 256, 0, stream>>>(combined, Wfin, bfin, out);
}